// Round 15
// baseline (868.950 us; speedup 1.0000x reference)
//
#include <hip/hip_runtime.h>
#include <math.h>

#define N_NODES 50000
#define DIM     128
#define NHEAD   8
#define HDIM    16
#define NLAYER  2
#define NTYPE   4
#define NREL    8
#define NEDGE   800000
#define RB      256
#define GN      8      // nodes per block in k_out_g
#define MT      32     // nodes per block in MFMA qkv kernel
#define NK      (N_NODES * NREL)
#define LHR     (NLAYER * NHEAD * NREL)

typedef __attribute__((ext_vector_type(8))) short bf16x8;   // 8 bf16 (4 VGPRs)
typedef __attribute__((ext_vector_type(4))) float f32x4;    // MFMA accumulator

__device__ __forceinline__ float blo(unsigned w) { return __uint_as_float(w << 16); }
__device__ __forceinline__ float bhi(unsigned w) { return __uint_as_float(w & 0xFFFF0000u); }
__device__ __forceinline__ unsigned short f2bf(float f) {
    unsigned b = __float_as_uint(f);
    b += 0x7FFFu + ((b >> 16) & 1u);
    return (unsigned short)(b >> 16);
}
__device__ __forceinline__ bf16x8 pack8(float4 x0, float4 x1) {
    bf16x8 r;
    r[0] = (short)f2bf(x0.x); r[1] = (short)f2bf(x0.y);
    r[2] = (short)f2bf(x0.z); r[3] = (short)f2bf(x0.w);
    r[4] = (short)f2bf(x1.x); r[5] = (short)f2bf(x1.y);
    r[6] = (short)f2bf(x1.z); r[7] = (short)f2bf(x1.w);
    return r;
}
__device__ __forceinline__ bf16x8 zero8() {
    bf16x8 r;
    #pragma unroll
    for (int j = 0; j < 8; j++) r[j] = 0;
    return r;
}

// ================= init: rank within type =================

__global__ void k_hist(const int* __restrict__ ntype, int* __restrict__ hist, int n) {
    __shared__ int cnt[NTYPE];
    if (threadIdx.x < NTYPE) cnt[threadIdx.x] = 0;
    __syncthreads();
    int i = blockIdx.x * RB + threadIdx.x;
    if (i < n) atomicAdd(&cnt[ntype[i]], 1);
    __syncthreads();
    if (threadIdx.x < NTYPE) hist[blockIdx.x * NTYPE + threadIdx.x] = cnt[threadIdx.x];
}

__global__ void k_prefix(const int* __restrict__ hist, int* __restrict__ off, int nb) {
    int t = threadIdx.x;
    if (t >= NTYPE) return;
    int acc = 0;
    for (int b = 0; b < nb; b++) { off[b * NTYPE + t] = acc; acc += hist[b * NTYPE + t]; }
}

__global__ void k_rank(const int* __restrict__ ntype, const int* __restrict__ off,
                       int* __restrict__ rank, int n) {
    __shared__ int ty[RB];
    int i = blockIdx.x * RB + threadIdx.x;
    int t = (i < n) ? ntype[i] : -1;
    ty[threadIdx.x] = t;
    __syncthreads();
    if (i < n) {
        int c = 0;
        for (int j = 0; j < (int)threadIdx.x; j++) c += (ty[j] == t);
        rank[i] = off[blockIdx.x * NTYPE + t] + c;
    }
}

__global__ void k_embed(const float* __restrict__ embed, const int* __restrict__ ntype,
                        const int* __restrict__ rank, float* __restrict__ h) {
    int i = blockIdx.x;
    int t = ntype[i], r = rank[i];
    h[(size_t)i * DIM + threadIdx.x] = embed[((size_t)t * N_NODES + r) * DIM + threadIdx.x];
}

__global__ void k_typeoff(const int* __restrict__ hist, const int* __restrict__ boff,
                          int nb, int* __restrict__ typeoff) {
    if (threadIdx.x == 0 && blockIdx.x == 0) {
        int acc = 0;
        for (int t = 0; t < NTYPE; t++) {
            typeoff[t] = acc;
            acc += boff[(nb - 1) * NTYPE + t] + hist[(nb - 1) * NTYPE + t];
        }
    }
}

__global__ void k_perm(const int* __restrict__ ntype, const int* __restrict__ rank,
                       const int* __restrict__ typeoff, int* __restrict__ perm,
                       int* __restrict__ iperm, int n) {
    int i = blockIdx.x * 256 + threadIdx.x;
    if (i < n) {
        int p = typeoff[ntype[i]] + rank[i];
        perm[p] = i;
        iperm[i] = p;
    }
}

// ================= (dst,etype)-sorted CSR build =================

__global__ void k_deg2(const int* __restrict__ dst, const int* __restrict__ etype,
                       int* __restrict__ deg) {
    int e = blockIdx.x * 256 + threadIdx.x;
    if (e < NEDGE) atomicAdd(&deg[dst[e] * NREL + etype[e]], 1);
}

__global__ void k_scan1(const int* __restrict__ deg, int* __restrict__ rs,
                        int* __restrict__ bsum, int n) {
    __shared__ int sh[256];
    int i = blockIdx.x * 256 + threadIdx.x;
    int v = (i < n) ? deg[i] : 0;
    sh[threadIdx.x] = v;
    __syncthreads();
    for (int off = 1; off < 256; off <<= 1) {
        int x = (threadIdx.x >= off) ? sh[threadIdx.x - off] : 0;
        __syncthreads();
        sh[threadIdx.x] += x;
        __syncthreads();
    }
    if (i < n) rs[i] = sh[threadIdx.x] - v;
    if (threadIdx.x == 255) bsum[blockIdx.x] = sh[255];
}

__global__ void k_scan2b(int* __restrict__ bsum, int nb) {
    __shared__ int sh[256];
    __shared__ int carry;
    if (threadIdx.x == 0) carry = 0;
    __syncthreads();
    for (int base = 0; base < nb; base += 256) {
        int i = base + threadIdx.x;
        int v = (i < nb) ? bsum[i] : 0;
        sh[threadIdx.x] = v;
        __syncthreads();
        for (int off = 1; off < 256; off <<= 1) {
            int x = (threadIdx.x >= off) ? sh[threadIdx.x - off] : 0;
            __syncthreads();
            sh[threadIdx.x] += x;
            __syncthreads();
        }
        if (i < nb) bsum[i] = sh[threadIdx.x] - v + carry;
        __syncthreads();
        if (threadIdx.x == 0) carry += sh[255];
        __syncthreads();
    }
}

__global__ void k_scan3(int* __restrict__ rs, const int* __restrict__ bsum, int n) {
    int i = blockIdx.x * 256 + threadIdx.x;
    if (i < n) rs[i] += bsum[blockIdx.x];
    if (i == 0) rs[n] = NEDGE;
}

__global__ void k_scatter2(const int* __restrict__ src, const int* __restrict__ dst,
                           const int* __restrict__ etype, const int* __restrict__ iperm,
                           const int* __restrict__ rs,
                           int* __restrict__ cur, int* __restrict__ epk) {
    int e = blockIdx.x * 256 + threadIdx.x;
    if (e < NEDGE) {
        int et = etype[e];
        int key = dst[e] * NREL + et;
        int p = atomicAdd(&cur[key], 1);
        epk[rs[key] + p] = iperm[src[e]] | (et << 24);
    }
}

// ================= weight prep =================

__global__ void k_rattB(const float* __restrict__ ratt, unsigned short* __restrict__ rattB) {
    int i = blockIdx.x * 256 + threadIdx.x;
    rattB[i] = f2bf(ratt[i]);
}

__global__ void k_rmsgT(const float* __restrict__ rmsg, float* __restrict__ rmsgT) {
    int b = blockIdx.x;
    int d = threadIdx.x >> 4, o = threadIdx.x & 15;
    rmsgT[b * 256 + o * 16 + d] = rmsg[b * 256 + d * 16 + o];
}

// zero-padded-K B-frag for 16x16x32 from rmsg (no scale)
__global__ void k_rmsgBP(const float* __restrict__ rmsg, unsigned short* __restrict__ out) {
    int b = blockIdx.x;                // (l*H + h)*R + et
    int i = threadIdx.x;               // lane*8 + e
    int ln = i >> 3, e = i & 7;
    int half = ln >> 4;
    unsigned short v = 0;
    if (half < 2) v = f2bf(rmsg[(size_t)b * 256 + (half * 8 + e) * 16 + (ln & 15)]);
    out[(size_t)b * 512 + i] = v;
}

// zero-padded-K B-frag from ratt, scaled by pri*0.25 (folds softmax scale)
__global__ void k_rattBP(const float* __restrict__ ratt, const float* __restrict__ rpri,
                         unsigned short* __restrict__ out) {
    int b = blockIdx.x;
    int i = threadIdx.x;
    int ln = i >> 3, e = i & 7;
    int half = ln >> 4;
    int et = b % NREL;
    int hh = (b / NREL) % NHEAD;
    int l = b / (NREL * NHEAD);
    float scale = rpri[(l * NHEAD + hh) * NREL + et] * 0.25f;
    unsigned short v = 0;
    if (half < 2) v = f2bf(ratt[(size_t)b * 256 + (half * 8 + e) * 16 + (ln & 15)] * scale);
    out[(size_t)b * 512 + i] = v;
}

// pack all L*3*T 128x128 typed mats into MFMA B-fragment bf16 layout
__global__ void k_packW_all(const float* __restrict__ Wk, const float* __restrict__ Wq,
                            const float* __restrict__ Wv, unsigned short* __restrict__ wpk) {
    int bid = blockIdx.x;              // (l*3+m)*NTYPE + t
    int t = bid & 3;
    int m = (bid >> 2) % 3;
    int l = bid / 12;
    const float* W = (m == 0 ? Wk : (m == 1 ? Wq : Wv)) + ((size_t)l * NTYPE + t) * 16384;
    unsigned short* ob = wpk + (size_t)bid * 16384;
    for (int idx = threadIdx.x; idx < 16384; idx += 256) {
        int ct = idx >> 11, kc = (idx >> 9) & 3, ln = (idx >> 3) & 63, j = idx & 7;
        int k = kc * 32 + ((ln >> 4) << 3) + j;
        int c = ct * 16 + (ln & 15);
        ob[idx] = f2bf(W[k * 128 + c]);
    }
}

// ======== MFMA typed k/q/v projection + table build — POS-SPACE OUTPUTS ========
// FULL=1: phase-2 builds combined tab[pos][et][{kwt|vt}] via zero-padded-K MFMA.
// FULL=0: R14 path (kb bf16 + vt via VALU).

template<int FULL>
__global__ __launch_bounds__(256) void k_qkv_mfma(
        const float* __restrict__ h, const int* __restrict__ perm, const int* __restrict__ ntype,
        const float* __restrict__ Wk, const float* __restrict__ Wq, const float* __restrict__ Wv,
        const unsigned short* __restrict__ WkB, const unsigned short* __restrict__ WqB,
        const unsigned short* __restrict__ WvB, const float* __restrict__ rmsgT,
        const unsigned short* __restrict__ rattBP, const unsigned short* __restrict__ rmsgBP,
        unsigned short* __restrict__ kb, float* __restrict__ qout,
        unsigned short* __restrict__ vt, unsigned short* __restrict__ tab, int n) {
    int tid = threadIdx.x;
    int base = blockIdx.x * MT;
    __shared__ int nodes_s[MT];
    __shared__ int types_s[MT];
    __shared__ float vs[MT][132];
    __shared__ float ks[MT][132];     // used only when FULL

    if (tid < MT) {
        int idx = base + tid;
        int nd = (idx < n) ? perm[idx] : -1;
        nodes_s[tid] = nd;
        types_s[tid] = (nd >= 0) ? ntype[nd] : -1;
    }
    __syncthreads();
    bool same = (nodes_s[MT - 1] >= 0) && (types_s[0] == types_s[MT - 1]);
    int l = tid & 63, w = tid >> 6;

    if (same) {
        int t = types_s[0];
        const unsigned short* wbk = WkB + (size_t)t * 16384;
        const unsigned short* wbq = WqB + (size_t)t * 16384;
        const unsigned short* wbv = WvB + (size_t)t * 16384;
        f32x4 acc[3][2][2];
        #pragma unroll
        for (int m = 0; m < 3; m++)
            #pragma unroll
            for (int a = 0; a < 2; a++)
                #pragma unroll
                for (int b = 0; b < 2; b++) {
                    acc[m][a][b][0] = 0.f; acc[m][a][b][1] = 0.f;
                    acc[m][a][b][2] = 0.f; acc[m][a][b][3] = 0.f;
                }
        #pragma unroll 1
        for (int kc = 0; kc < 4; kc++) {
            int koff = kc * 32 + ((l >> 4) << 3);
            int r0 = l & 15;
            const float4* p0 = (const float4*)(h + (size_t)nodes_s[r0] * DIM + koff);
            bf16x8 a0 = pack8(p0[0], p0[1]);
            const float4* p1 = (const float4*)(h + (size_t)nodes_s[16 + r0] * DIM + koff);
            bf16x8 a1 = pack8(p1[0], p1[1]);
            #pragma unroll
            for (int cti = 0; cti < 2; cti++) {
                int boff = ((w * 2 + cti) * 4 + kc) * 512 + l * 8;
                bf16x8 bk = *(const bf16x8*)(wbk + boff);
                acc[0][0][cti] = __builtin_amdgcn_mfma_f32_16x16x32_bf16(a0, bk, acc[0][0][cti], 0, 0, 0);
                acc[0][1][cti] = __builtin_amdgcn_mfma_f32_16x16x32_bf16(a1, bk, acc[0][1][cti], 0, 0, 0);
                bf16x8 bq = *(const bf16x8*)(wbq + boff);
                acc[1][0][cti] = __builtin_amdgcn_mfma_f32_16x16x32_bf16(a0, bq, acc[1][0][cti], 0, 0, 0);
                acc[1][1][cti] = __builtin_amdgcn_mfma_f32_16x16x32_bf16(a1, bq, acc[1][1][cti], 0, 0, 0);
                bf16x8 bv = *(const bf16x8*)(wbv + boff);
                acc[2][0][cti] = __builtin_amdgcn_mfma_f32_16x16x32_bf16(a0, bv, acc[2][0][cti], 0, 0, 0);
                acc[2][1][cti] = __builtin_amdgcn_mfma_f32_16x16x32_bf16(a1, bv, acc[2][1][cti], 0, 0, 0);
            }
        }
        // D lane map: col = lane&15, row = (lane>>4)*4 + r (pos-space streaming)
        #pragma unroll
        for (int mt = 0; mt < 2; mt++)
            #pragma unroll
            for (int cti = 0; cti < 2; cti++) {
                int col = w * 32 + cti * 16 + (l & 15);
                #pragma unroll
                for (int r = 0; r < 4; r++) {
                    int row = mt * 16 + ((l >> 4) << 2) + r;
                    size_t p = (size_t)(base + row) * DIM + col;
                    qout[p] = acc[1][mt][cti][r];
                    vs[row][col] = acc[2][mt][cti][r];
                    if constexpr (FULL) ks[row][col] = acc[0][mt][cti][r];
                    else                kb[p] = f2bf(acc[0][mt][cti][r]);
                }
            }
    } else {
        // scalar fallback (type-boundary / tail blocks)
        int o = tid & 127, half = tid >> 7;
        for (int nn = half; nn < MT; nn += 2) {
            int nd = nodes_s[nn];
            if (nd < 0) { vs[nn][o] = 0.f; if constexpr (FULL) ks[nn][o] = 0.f; continue; }
            int t = types_s[nn];
            const float* wk = Wk + (size_t)t * 16384;
            const float* wq = Wq + (size_t)t * 16384;
            const float* wv = Wv + (size_t)t * 16384;
            float ak = 0.f, aq = 0.f, av = 0.f;
            for (int d = 0; d < DIM; d++) {
                float xv = h[(size_t)nd * DIM + d];
                ak = fmaf(xv, wk[d * DIM + o], ak);
                aq = fmaf(xv, wq[d * DIM + o], aq);
                av = fmaf(xv, wv[d * DIM + o], av);
            }
            size_t p = (size_t)(base + nn) * DIM + o;
            qout[p] = aq;
            vs[nn][o] = av;
            if constexpr (FULL) ks[nn][o] = ak;
            else                kb[p] = f2bf(ak);
        }
    }
    __syncthreads();

    if constexpr (FULL) {
        // ---- phase 2 (MFMA): tab[pos][et] = { kwt (k·Watt·pri/4) | vt (v·Wmsg) } ----
        int half = l >> 4;
        #pragma unroll 1
        for (int tbl = 0; tbl < 2; tbl++) {
            const unsigned short* bp = tbl ? rmsgBP : rattBP;
            bf16x8 afr[2][2];
            #pragma unroll
            for (int hh2 = 0; hh2 < 2; hh2++) {
                int hh = w * 2 + hh2;
                #pragma unroll
                for (int nt = 0; nt < 2; nt++) {
                    if (half < 2) {
                        const float* srow = tbl ? &vs[nt * 16 + (l & 15)][hh * HDIM + half * 8]
                                                : &ks[nt * 16 + (l & 15)][hh * HDIM + half * 8];
                        const float4* vp = (const float4*)srow;
                        afr[hh2][nt] = pack8(vp[0], vp[1]);
                    } else afr[hh2][nt] = zero8();
                }
            }
            #pragma unroll 1
            for (int hh2 = 0; hh2 < 2; hh2++) {
                int hh = w * 2 + hh2;
                #pragma unroll 1
                for (int et = 0; et < NREL; et++) {
                    bf16x8 bfr = *(const bf16x8*)(bp + ((size_t)(hh * NREL + et) * 64 + l) * 8);
                    #pragma unroll
                    for (int nt = 0; nt < 2; nt++) {
                        f32x4 d4 = {0.f, 0.f, 0.f, 0.f};
                        d4 = __builtin_amdgcn_mfma_f32_16x16x32_bf16(afr[hh2][nt], bfr, d4, 0, 0, 0);
                        #pragma unroll
                        for (int r = 0; r < 4; r++) {
                            int row = nt * 16 + half * 4 + r;
                            if (base + row < n)
                                tab[((size_t)(base + row) * NREL + et) * 256 + tbl * 128
                                    + hh * HDIM + (l & 15)] = f2bf(d4[r]);
                        }
                    }
                }
            }
        }
    } else {
        // ---- phase 2 (VALU, R14): vt[pos][et][o], contiguous streaming stores ----
        int o = tid & 127, half = tid >> 7;
        int hh = o >> 4, oo = o & 15;
        #pragma unroll 1
        for (int et = 0; et < NREL; et++) {
            const float4* w4 = (const float4*)(rmsgT + ((size_t)(hh * NREL + et) * HDIM + oo) * HDIM);
            float4 w0 = w4[0], w1 = w4[1], w2 = w4[2], w3 = w4[3];
            for (int i = 0; i < 16; i++) {
                int nn = half * 16 + i;
                if (base + nn >= n) continue;
                const float4* v4 = (const float4*)&vs[nn][hh * HDIM];
                float4 v0 = v4[0], v1 = v4[1], v2 = v4[2], v3 = v4[3];
                float a2 = v0.x*w0.x + v0.y*w0.y + v0.z*w0.z + v0.w*w0.w
                         + v1.x*w1.x + v1.y*w1.y + v1.z*w1.z + v1.w*w1.w
                         + v2.x*w2.x + v2.y*w2.y + v2.z*w2.z + v2.w*w2.w
                         + v3.x*w3.x + v3.y*w3.y + v3.z*w3.z + v3.w*w3.w;
                vt[((size_t)(base + nn) * NREL + et) * DIM + o] = f2bf(a2);
            }
        }
    }
}

// ======= fused attention v12 (FULL path): kwt gather, no u-compute =======

__global__ __launch_bounds__(128) void k_fused12(
        const unsigned short* __restrict__ tab, const float* __restrict__ qbuf,
        const int* __restrict__ perm,
        const int* __restrict__ rs2, const int* __restrict__ epk,
        float* __restrict__ agg) {
    int b = blockIdx.x;
    int node = perm[b];
    int tid = threadIdx.x;
    int hh = tid >> 4, oo = tid & 15;
    int wv = tid >> 6;
    int hl = hh & 3;

    __shared__ float q_s[DIM];
    __shared__ float a_sw[2][4][HDIM + 1];
    __shared__ int   es_sw[2][HDIM];

    int e0 = rs2[node * NREL];
    int e1 = rs2[node * NREL + NREL];
    if (e0 == e1) { agg[(size_t)b * DIM + tid] = 0.f; return; }

    q_s[tid] = qbuf[(size_t)b * DIM + tid];
    const float4* q4 = (const float4*)&q_s[hh * HDIM];   // intra-wave LDS, in-order
    float4 q0 = q4[0], q1 = q4[1], q2 = q4[2], q3 = q4[3];

    float m_h = -1e30f, s_h = 0.f, out = 0.f;

    for (int w0e = e0; w0e < e1; w0e += HDIM) {
        int cnt = min(HDIM, e1 - w0e);
        float a = -1e30f;
        int pk = 0;
        if (oo < cnt) {
            pk = epk[w0e + oo];
            int sv = pk & 0x00FFFFFF;
            int et = ((unsigned)pk) >> 24;
            const uint4* kw = (const uint4*)(tab + ((size_t)sv * NREL + et) * 256 + hh * HDIM);
            uint4 ka = kw[0], kc = kw[1];
            a = blo(ka.x)*q0.x + bhi(ka.x)*q0.y + blo(ka.y)*q0.z + bhi(ka.y)*q0.w
              + blo(ka.z)*q1.x + bhi(ka.z)*q1.y + blo(ka.w)*q1.z + bhi(ka.w)*q1.w
              + blo(kc.x)*q2.x + bhi(kc.x)*q2.y + blo(kc.y)*q2.z + bhi(kc.y)*q2.w
              + blo(kc.z)*q3.x + bhi(kc.z)*q3.y + blo(kc.w)*q3.z + bhi(kc.w)*q3.w;
        }
        if (hl == 0) es_sw[wv][oo] = pk;
        float cmax = a;
        cmax = fmaxf(cmax, __shfl_xor(cmax, 1));
        cmax = fmaxf(cmax, __shfl_xor(cmax, 2));
        cmax = fmaxf(cmax, __shfl_xor(cmax, 4));
        cmax = fmaxf(cmax, __shfl_xor(cmax, 8));
        float m_t = (cmax > m_h + 12.f) ? cmax : m_h;   // deferred rescale
        float r = __expf(m_h - m_t);
        s_h *= r; out *= r; m_h = m_t;
        float p = (oo < cnt) ? __expf(a - m_h) : 0.f;
        float ps = p;
        ps += __shfl_xor(ps, 1);
        ps += __shfl_xor(ps, 2);
        ps += __shfl_xor(ps, 4);
        ps += __shfl_xor(ps, 8);
        s_h += ps;
        a_sw[wv][hl][oo] = p;
        for (int c = 0; c < cnt; c++) {
            float pc = a_sw[wv][hl][c];
            int pkc = es_sw[wv][c];
            int sv = pkc & 0x00FFFFFF;
            int et = ((unsigned)pkc) >> 24;
            unsigned short uv = tab[((size_t)sv * NREL + et) * 256 + 128 + tid];
            out = fmaf(pc, __uint_as_float((unsigned)uv << 16), out);
        }
    }

    agg[(size_t)b * DIM + tid] = out / (s_h + 1e-9f);
}

// ======= fused attention v11 (fallback path, R14-identical) =======

__global__ __launch_bounds__(128) void k_fused11(
        const unsigned short* __restrict__ kb, const float* __restrict__ qbuf,
        const unsigned short* __restrict__ vt,
        const int* __restrict__ perm,
        const int* __restrict__ rs2, const int* __restrict__ epk,
        const unsigned short* __restrict__ rattB, const float* __restrict__ rpri,
        float* __restrict__ agg) {
    int b = blockIdx.x;
    int node = perm[b];
    int tid = threadIdx.x;
    int hh = tid >> 4, oo = tid & 15;
    int wv = tid >> 6;
    int hl = hh & 3;

    __shared__ float q_s[DIM];
    __shared__ float u_s[NREL][NHEAD * HDIM + 4];
    __shared__ float a_sw[2][4][HDIM + 1];
    __shared__ int   es_sw[2][HDIM];

    int e0 = rs2[node * NREL];
    int e1 = rs2[node * NREL + NREL];
    if (e0 == e1) { agg[(size_t)b * DIM + tid] = 0.f; return; }

    q_s[tid] = qbuf[(size_t)b * DIM + tid];
    {
        const float4* q4 = (const float4*)&q_s[hh * HDIM];
        float4 q0 = q4[0], q1 = q4[1], q2 = q4[2], q3 = q4[3];
        #pragma unroll
        for (int et = 0; et < NREL; et++) {
            const uint4* wB = (const uint4*)(rattB + ((size_t)(hh * NREL + et) * HDIM + oo) * HDIM);
            uint4 wa = wB[0], wb = wB[1];
            float s = blo(wa.x)*q0.x + bhi(wa.x)*q0.y + blo(wa.y)*q0.z + bhi(wa.y)*q0.w
                    + blo(wa.z)*q1.x + bhi(wa.z)*q1.y + blo(wa.w)*q1.z + bhi(wa.w)*q1.w
                    + blo(wb.x)*q2.x + bhi(wb.x)*q2.y + blo(wb.y)*q2.z + bhi(wb.y)*q2.w
                    + blo(wb.z)*q3.x + bhi(wb.z)*q3.y + blo(wb.w)*q3.z + bhi(wb.w)*q3.w;
            u_s[et][tid] = s * rpri[hh * NREL + et] * 0.25f;
        }
    }

    float m_h = -1e30f, s_h = 0.f, out = 0.f;

    for (int w0e = e0; w0e < e1; w0e += HDIM) {
        int cnt = min(HDIM, e1 - w0e);
        float a = -1e30f;
        int pk = 0;
        if (oo < cnt) {
            pk = epk[w0e + oo];
            int sv = pk & 0x00FFFFFF;
            int et = ((unsigned)pk) >> 24;
            const uint4* kr = (const uint4*)(kb + (size_t)sv * DIM + hh * HDIM);
            uint4 ka = kr[0], kc = kr[1];
            const float4* u4 = (const float4*)&u_s[et][hh * HDIM];
            float4 u0 = u4[0], u1 = u4[1], u2 = u4[2], u3 = u4[3];
            a = blo(ka.x)*u0.x + bhi(ka.x)*u0.y + blo(ka.y)*u0.z + bhi(ka.y)*u0.w
              + blo(ka.z)*u1.x + bhi(ka.z)*u1.y + blo(ka.w)*u1.z + bhi(ka.w)*u1.w
              + blo(kc.x)*u2.x + bhi(kc.x)*u2.y + blo(kc.y)*u2.z + bhi(kc.y)*u2.w
              + blo(kc.z)*u3.x + bhi(kc.z)*u3.y + blo(kc.w)*u3.z + bhi(kc.w)*u3.w;
        }
        if (hl == 0) es_sw[wv][oo] = pk;
        float cmax = a;
        cmax = fmaxf(cmax, __shfl_xor(cmax, 1));
        cmax = fmaxf(cmax, __shfl_xor(cmax, 2));
        cmax = fmaxf(cmax, __shfl_xor(cmax, 4));
        cmax = fmaxf(cmax, __shfl_xor(cmax, 8));
        float m_t = (cmax > m_h + 12.f) ? cmax : m_h;
        float r = __expf(m_h - m_t);
        s_h *= r; out *= r; m_h = m_t;
        float p = (oo < cnt) ? __expf(a - m_h) : 0.f;
        float ps = p;
        ps += __shfl_xor(ps, 1);
        ps += __shfl_xor(ps, 2);
        ps += __shfl_xor(ps, 4);
        ps += __shfl_xor(ps, 8);
        s_h += ps;
        a_sw[wv][hl][oo] = p;
        for (int c = 0; c < cnt; c++) {
            float pc = a_sw[wv][hl][c];
            int pkc = es_sw[wv][c];
            int sv = pkc & 0x00FFFFFF;
            int et = ((unsigned)pkc) >> 24;
            unsigned short uv = vt[((size_t)sv * NREL + et) * DIM + tid];
            out = fmaf(pc, __uint_as_float((unsigned)uv << 16), out);
        }
    }

    agg[(size_t)b * DIM + tid] = out / (s_h + 1e-9f);
}

// ====== output projection + skip + LN + residual (pos-space agg read) ======

__global__ __launch_bounds__(128) void k_out_g(
        const float* __restrict__ agg, float* __restrict__ h,
        const int* __restrict__ perm, const int* __restrict__ ntype,
        const float* __restrict__ Wa, const float* __restrict__ skip,
        const float* __restrict__ ln_g, const float* __restrict__ ln_b, int n) {
    int o = threadIdx.x;
    int base = blockIdx.x * GN;
    __shared__ float xs[GN][DIM];
    __shared__ float hcs[GN][DIM + 1];
    __shared__ int nodes[GN];
    __shared__ int types[GN];
    __shared__ float mu_s[GN], rs_s[GN];
    if (o < GN) {
        int idx = base + o;
        int nd = (idx < n) ? perm[idx] : -1;
        nodes[o] = nd;
        types[o] = (nd >= 0) ? ntype[nd] : -1;
    }
    __syncthreads();
    #pragma unroll
    for (int nn = 0; nn < GN; nn++)
        if (nodes[nn] >= 0) xs[nn][o] = agg[(size_t)(base + nn) * DIM + o];
    __syncthreads();
    bool same = (nodes[GN - 1] >= 0) && (types[0] == types[GN - 1]);
    if (same) {
        int t = types[0];
        const float* w = Wa + (size_t)t * DIM * DIM;
        float acc[GN];
        #pragma unroll
        for (int nn = 0; nn < GN; nn++) acc[nn] = 0.f;
        for (int d = 0; d < DIM; d++) {
            float wv = w[d * DIM + o];
            #pragma unroll
            for (int nn = 0; nn < GN; nn++) acc[nn] = fmaf(xs[nn][d], wv, acc[nn]);
        }
        float alpha = 1.f / (1.f + __expf(-skip[t]));
        #pragma unroll
        for (int nn = 0; nn < GN; nn++) {
            float hp = h[(size_t)nodes[nn] * DIM + o];
            hcs[nn][o] = acc[nn] * alpha + hp * (1.f - alpha);
        }
    } else {
        #pragma unroll 1
        for (int nn = 0; nn < GN; nn++) {
            if (nodes[nn] < 0) continue;
            int t = types[nn];
            const float* w = Wa + (size_t)t * DIM * DIM;
            float a0 = 0.f;
            for (int d = 0; d < DIM; d++) a0 = fmaf(xs[nn][d], w[d * DIM + o], a0);
            float alpha = 1.f / (1.f + __expf(-skip[t]));
            float hp = h[(size_t)nodes[nn] * DIM + o];
            hcs[nn][o] = a0 * alpha + hp * (1.f - alpha);
        }
    }
    __syncthreads();
    {
        int g = o >> 4, j = o & 15;
        if (nodes[g] >= 0) {
            float s = 0.f;
            for (int d = j; d < DIM; d += 16) s += hcs[g][d];
            #pragma unroll
            for (int m = 1; m < 16; m <<= 1) s += __shfl_xor(s, m);
            float mu = s * (1.f / DIM);
            float v = 0.f;
            for (int d = j; d < DIM; d += 16) { float dv = hcs[g][d] - mu; v = fmaf(dv, dv, v); }
            #pragma unroll
            for (int m = 1; m < 16; m <<= 1) v += __shfl_xor(v, m);
            if (j == 0) { mu_s[g] = mu; rs_s[g] = rsqrtf(v * (1.f / DIM) + 1e-5f); }
        }
    }
    __syncthreads();
    float g_o = ln_g[o], b_o = ln_b[o];
    #pragma unroll
    for (int nn = 0; nn < GN; nn++) {
        if (nodes[nn] >= 0) {
            float hp = h[(size_t)nodes[nn] * DIM + o];
            h[(size_t)nodes[nn] * DIM + o] = (hcs[nn][o] - mu_s[nn]) * rs_s[nn] * g_o + b_o + hp;
        }
    }
}

// ================= host =================

extern "C" void kernel_launch(void* const* d_in, const int* in_sizes, int n_in,
                              void* d_out, int out_size, void* d_ws, size_t ws_size,
                              hipStream_t stream) {
    const float* embed = (const float*)d_in[0];
    const float* Wk    = (const float*)d_in[1];
    const float* Wq    = (const float*)d_in[2];
    const float* Wv    = (const float*)d_in[3];
    const float* Wa    = (const float*)d_in[4];
    const float* ratt  = (const float*)d_in[5];
    const float* rmsg  = (const float*)d_in[6];
    const float* rpri  = (const float*)d_in[7];
    const float* skip  = (const float*)d_in[8];
    const float* ln_g  = (const float*)d_in[9];
    const float* ln_b  = (const float*)d_in[10];
    const int*   src   = (const int*)d_in[11];
    const int*   dst   = (const int*)d_in[12];
    const int*   ntype = (const int*)d_in[13];
    const int*   etype = (const int*)d_in[14];

    float* h = (float*)d_out;

    const size_t ND = (size_t)N_NODES * DIM;
    const int nb = (N_NODES + RB - 1) / RB;
    unsigned short* kb = (unsigned short*)d_ws;          // ND bf16 (fallback)
    float* qbuf = (float*)(kb + ND);                     // ND f32 (pos-space; aliased agg)
    int* rs2  = (int*)(qbuf + ND);               // NK+1
    int* deg2 = rs2 + (NK + 1);                  // NK
    int* cur2 = deg2 + NK;                       // NK
    int* epk  = cur2 + NK;                       // E
    int* bsum = epk + NEDGE;                     // 2048
    int* rank = bsum + 2048;                     // N
    int* hist = rank + N_NODES;                  // nb*NTYPE
    int* boff = hist + nb * NTYPE;               // nb*NTYPE
    int* typeoff = boff + nb * NTYPE;            // NTYPE
    int* perm = typeoff + NTYPE;                 // N
    int* iperm = perm + N_NODES;                 // N
    float* rmsgT = (float*)(iperm + N_NODES);    // LHR*256 f32
    unsigned short* rattB  = (unsigned short*)(rmsgT + (size_t)LHR * 256);  // LHR*256
    unsigned short* rattBP = rattB + (size_t)LHR * 256;                     // LHR*512
    unsigned short* rmsgBP = rattBP + (size_t)LHR * 512;                    // LHR*512
    unsigned short* wpk = rmsgBP + (size_t)LHR * 512;                       // L*3*T*16384
    unsigned short* vt  = wpk + (size_t)NLAYER * 3 * NTYPE * 16384;         // N*R*128 (fallback)
    unsigned short* tab = vt;                                               // N*R*256 (full)
    size_t need_full = (size_t)((char*)(tab + (size_t)N_NODES * NREL * 256) - (char*)d_ws);
    const bool FULL = (ws_size >= need_full);
    float* agg = qbuf;

    const int EB = (NEDGE + 255) / 256;
    const int nb2 = (NK + 255) / 256;

    // ---- init: rank-within-type, embedding, type permutation ----
    k_hist<<<nb, RB, 0, stream>>>(ntype, hist, N_NODES);
    k_prefix<<<1, 64, 0, stream>>>(hist, boff, nb);
    k_rank<<<nb, RB, 0, stream>>>(ntype, boff, rank, N_NODES);
    k_embed<<<N_NODES, DIM, 0, stream>>>(embed, ntype, rank, h);
    k_typeoff<<<1, 64, 0, stream>>>(hist, boff, nb, typeoff);
    k_perm<<<nb, 256, 0, stream>>>(ntype, rank, typeoff, perm, iperm, N_NODES);

    // ---- (dst,etype)-sorted CSR build ----
    hipMemsetAsync(deg2, 0, (size_t)NK * sizeof(int), stream);
    hipMemsetAsync(cur2, 0, (size_t)NK * sizeof(int), stream);
    k_deg2<<<EB, 256, 0, stream>>>(dst, etype, deg2);
    k_scan1<<<nb2, 256, 0, stream>>>(deg2, rs2, bsum, NK);
    k_scan2b<<<1, 256, 0, stream>>>(bsum, nb2);
    k_scan3<<<nb2, 256, 0, stream>>>(rs2, bsum, NK);
    k_scatter2<<<EB, 256, 0, stream>>>(src, dst, etype, iperm, rs2, cur2, epk);

    // ---- weight prep (all layers, one launch each) ----
    k_rattB<<<LHR, 256, 0, stream>>>(ratt, rattB);
    k_rmsgT<<<LHR, 256, 0, stream>>>(rmsg, rmsgT);
    k_rattBP<<<LHR, 512, 0, stream>>>(ratt, rpri, rattBP);
    k_rmsgBP<<<LHR, 512, 0, stream>>>(rmsg, rmsgBP);
    k_packW_all<<<NLAYER * 3 * NTYPE, 256, 0, stream>>>(Wk, Wq, Wv, wpk);

    const int NGB = N_NODES / GN;            // 6250
    const int NMB = (N_NODES + MT - 1) / MT; // 1563

    for (int l = 0; l < NLAYER; l++) {
        const float* Wk_l = Wk + (size_t)l * NTYPE * DIM * DIM;
        const float* Wq_l = Wq + (size_t)l * NTYPE * DIM * DIM;
        const float* Wv_l = Wv + (size_t)l * NTYPE * DIM * DIM;
        const float* Wa_l = Wa + (size_t)l * NTYPE * DIM * DIM;
        const unsigned short* wkB_l = wpk + ((size_t)l * 3 + 0) * NTYPE * 16384;
        const unsigned short* wqB_l = wpk + ((size_t)l * 3 + 1) * NTYPE * 16384;
        const unsigned short* wvB_l = wpk + ((size_t)l * 3 + 2) * NTYPE * 16384;
        const unsigned short* rattB_l  = rattB + (size_t)l * NHEAD * NREL * 256;
        const unsigned short* rattBP_l = rattBP + (size_t)l * NHEAD * NREL * 512;
        const unsigned short* rmsgBP_l = rmsgBP + (size_t)l * NHEAD * NREL * 512;
        const float* rmsgT_l = rmsgT + (size_t)l * NHEAD * NREL * 256;
        const float* rpri_l = rpri + (size_t)l * NHEAD * NREL;
        const float* skip_l = skip + (size_t)l * NTYPE;
        const float* g_l = ln_g + (size_t)l * DIM;
        const float* b_l = ln_b + (size_t)l * DIM;

        if (FULL) {
            k_qkv_mfma<1><<<NMB, 256, 0, stream>>>(h, perm, ntype, Wk_l, Wq_l, Wv_l,
                                                   wkB_l, wqB_l, wvB_l, rmsgT_l,
                                                   rattBP_l, rmsgBP_l,
                                                   kb, qbuf, vt, tab, N_NODES);
            k_fused12<<<N_NODES, 128, 0, stream>>>(tab, qbuf, perm, rs2, epk, agg);
        } else {
            k_qkv_mfma<0><<<NMB, 256, 0, stream>>>(h, perm, ntype, Wk_l, Wq_l, Wv_l,
                                                   wkB_l, wqB_l, wvB_l, rmsgT_l,
                                                   rattBP_l, rmsgBP_l,
                                                   kb, qbuf, vt, tab, N_NODES);
            k_fused11<<<N_NODES, 128, 0, stream>>>(kb, qbuf, vt, perm, rs2, epk,
                                                   rattB_l, rpri_l, agg);
        }
        k_out_g<<<NGB, 128, 0, stream>>>(agg, h, perm, ntype, Wa_l, skip_l, g_l, b_l, N_NODES);
    }
}

// Round 16
// 782.084 us; speedup vs baseline: 1.1111x; 1.1111x over previous
//
#include <hip/hip_runtime.h>
#include <math.h>

#define N_NODES 50000
#define DIM     128
#define NHEAD   8
#define HDIM    16
#define NLAYER  2
#define NTYPE   4
#define NREL    8
#define NEDGE   800000
#define RB      256
#define GN      8      // nodes per block in k_out_g
#define MT      32     // nodes per block in MFMA qkv kernel
#define NK      (N_NODES * NREL)
#define LHR     (NLAYER * NHEAD * NREL)

typedef __attribute__((ext_vector_type(8))) short bf16x8;   // 8 bf16 (4 VGPRs)
typedef __attribute__((ext_vector_type(4))) float f32x4;    // MFMA accumulator

__device__ __forceinline__ float blo(unsigned w) { return __uint_as_float(w << 16); }
__device__ __forceinline__ float bhi(unsigned w) { return __uint_as_float(w & 0xFFFF0000u); }
__device__ __forceinline__ unsigned short f2bf(float f) {
    unsigned b = __float_as_uint(f);
    b += 0x7FFFu + ((b >> 16) & 1u);
    return (unsigned short)(b >> 16);
}
__device__ __forceinline__ bf16x8 pack8(float4 x0, float4 x1) {
    bf16x8 r;
    r[0] = (short)f2bf(x0.x); r[1] = (short)f2bf(x0.y);
    r[2] = (short)f2bf(x0.z); r[3] = (short)f2bf(x0.w);
    r[4] = (short)f2bf(x1.x); r[5] = (short)f2bf(x1.y);
    r[6] = (short)f2bf(x1.z); r[7] = (short)f2bf(x1.w);
    return r;
}

// ================= init: rank within type =================

__global__ void k_hist(const int* __restrict__ ntype, int* __restrict__ hist, int n) {
    __shared__ int cnt[NTYPE];
    if (threadIdx.x < NTYPE) cnt[threadIdx.x] = 0;
    __syncthreads();
    int i = blockIdx.x * RB + threadIdx.x;
    if (i < n) atomicAdd(&cnt[ntype[i]], 1);
    __syncthreads();
    if (threadIdx.x < NTYPE) hist[blockIdx.x * NTYPE + threadIdx.x] = cnt[threadIdx.x];
}

__global__ void k_prefix(const int* __restrict__ hist, int* __restrict__ off, int nb) {
    int t = threadIdx.x;
    if (t >= NTYPE) return;
    int acc = 0;
    for (int b = 0; b < nb; b++) { off[b * NTYPE + t] = acc; acc += hist[b * NTYPE + t]; }
}

__global__ void k_rank(const int* __restrict__ ntype, const int* __restrict__ off,
                       int* __restrict__ rank, int n) {
    __shared__ int ty[RB];
    int i = blockIdx.x * RB + threadIdx.x;
    int t = (i < n) ? ntype[i] : -1;
    ty[threadIdx.x] = t;
    __syncthreads();
    if (i < n) {
        int c = 0;
        for (int j = 0; j < (int)threadIdx.x; j++) c += (ty[j] == t);
        rank[i] = off[blockIdx.x * NTYPE + t] + c;
    }
}

__global__ void k_embed(const float* __restrict__ embed, const int* __restrict__ ntype,
                        const int* __restrict__ rank, float* __restrict__ h) {
    int i = blockIdx.x;
    int t = ntype[i], r = rank[i];
    h[(size_t)i * DIM + threadIdx.x] = embed[((size_t)t * N_NODES + r) * DIM + threadIdx.x];
}

__global__ void k_typeoff(const int* __restrict__ hist, const int* __restrict__ boff,
                          int nb, int* __restrict__ typeoff) {
    if (threadIdx.x == 0 && blockIdx.x == 0) {
        int acc = 0;
        for (int t = 0; t < NTYPE; t++) {
            typeoff[t] = acc;
            acc += boff[(nb - 1) * NTYPE + t] + hist[(nb - 1) * NTYPE + t];
        }
    }
}

__global__ void k_perm(const int* __restrict__ ntype, const int* __restrict__ rank,
                       const int* __restrict__ typeoff, int* __restrict__ perm,
                       int* __restrict__ iperm, int n) {
    int i = blockIdx.x * 256 + threadIdx.x;
    if (i < n) {
        int p = typeoff[ntype[i]] + rank[i];
        perm[p] = i;
        iperm[i] = p;
    }
}

// ================= (dst,etype)-sorted CSR build =================

__global__ void k_deg2(const int* __restrict__ dst, const int* __restrict__ etype,
                       int* __restrict__ deg) {
    int e = blockIdx.x * 256 + threadIdx.x;
    if (e < NEDGE) atomicAdd(&deg[dst[e] * NREL + etype[e]], 1);
}

__global__ void k_scan1(const int* __restrict__ deg, int* __restrict__ rs,
                        int* __restrict__ bsum, int n) {
    __shared__ int sh[256];
    int i = blockIdx.x * 256 + threadIdx.x;
    int v = (i < n) ? deg[i] : 0;
    sh[threadIdx.x] = v;
    __syncthreads();
    for (int off = 1; off < 256; off <<= 1) {
        int x = (threadIdx.x >= off) ? sh[threadIdx.x - off] : 0;
        __syncthreads();
        sh[threadIdx.x] += x;
        __syncthreads();
    }
    if (i < n) rs[i] = sh[threadIdx.x] - v;
    if (threadIdx.x == 255) bsum[blockIdx.x] = sh[255];
}

__global__ void k_scan2b(int* __restrict__ bsum, int nb) {
    __shared__ int sh[256];
    __shared__ int carry;
    if (threadIdx.x == 0) carry = 0;
    __syncthreads();
    for (int base = 0; base < nb; base += 256) {
        int i = base + threadIdx.x;
        int v = (i < nb) ? bsum[i] : 0;
        sh[threadIdx.x] = v;
        __syncthreads();
        for (int off = 1; off < 256; off <<= 1) {
            int x = (threadIdx.x >= off) ? sh[threadIdx.x - off] : 0;
            __syncthreads();
            sh[threadIdx.x] += x;
            __syncthreads();
        }
        if (i < nb) bsum[i] = sh[threadIdx.x] - v + carry;
        __syncthreads();
        if (threadIdx.x == 0) carry += sh[255];
        __syncthreads();
    }
}

__global__ void k_scan3(int* __restrict__ rs, const int* __restrict__ bsum, int n) {
    int i = blockIdx.x * 256 + threadIdx.x;
    if (i < n) rs[i] += bsum[blockIdx.x];
    if (i == 0) rs[n] = NEDGE;
}

__global__ void k_scatter2(const int* __restrict__ src, const int* __restrict__ dst,
                           const int* __restrict__ etype, const int* __restrict__ iperm,
                           const int* __restrict__ rs,
                           int* __restrict__ cur, int* __restrict__ epk) {
    int e = blockIdx.x * 256 + threadIdx.x;
    if (e < NEDGE) {
        int et = etype[e];
        int key = dst[e] * NREL + et;
        int p = atomicAdd(&cur[key], 1);
        epk[rs[key] + p] = iperm[src[e]] | (et << 24);
    }
}

// ================= weight prep =================

__global__ void k_rattB(const float* __restrict__ ratt, unsigned short* __restrict__ rattB) {
    int i = blockIdx.x * 256 + threadIdx.x;
    rattB[i] = f2bf(ratt[i]);
}

__global__ void k_rmsgT(const float* __restrict__ rmsg, float* __restrict__ rmsgT) {
    int b = blockIdx.x;
    int d = threadIdx.x >> 4, o = threadIdx.x & 15;
    rmsgT[b * 256 + o * 16 + d] = rmsg[b * 256 + d * 16 + o];
}

// pri-scaled transposed ratt: rattT[b][o][d] = ratt[b][d][o] * pri * 0.25
__global__ void k_rattT(const float* __restrict__ ratt, const float* __restrict__ rpri,
                        float* __restrict__ rattT) {
    int b = blockIdx.x;                // (l*H + h)*R + et
    int d = threadIdx.x >> 4, o = threadIdx.x & 15;
    int et = b % NREL;
    int hh = (b / NREL) % NHEAD;
    int l = b / (NREL * NHEAD);
    float scale = rpri[(l * NHEAD + hh) * NREL + et] * 0.25f;
    rattT[b * 256 + o * 16 + d] = ratt[b * 256 + d * 16 + o] * scale;
}

// pack all L*3*T 128x128 typed mats into MFMA B-fragment bf16 layout
__global__ void k_packW_all(const float* __restrict__ Wk, const float* __restrict__ Wq,
                            const float* __restrict__ Wv, unsigned short* __restrict__ wpk) {
    int bid = blockIdx.x;              // (l*3+m)*NTYPE + t
    int t = bid & 3;
    int m = (bid >> 2) % 3;
    int l = bid / 12;
    const float* W = (m == 0 ? Wk : (m == 1 ? Wq : Wv)) + ((size_t)l * NTYPE + t) * 16384;
    unsigned short* ob = wpk + (size_t)bid * 16384;
    for (int idx = threadIdx.x; idx < 16384; idx += 256) {
        int ct = idx >> 11, kc = (idx >> 9) & 3, ln = (idx >> 3) & 63, j = idx & 7;
        int k = kc * 32 + ((ln >> 4) << 3) + j;
        int c = ct * 16 + (ln & 15);
        ob[idx] = f2bf(W[k * 128 + c]);
    }
}

// ======== MFMA typed k/q/v projection + VALU tab build — POS-SPACE STREAMING ========
// Phase 1 (MFMA): k,q,v for 32 same-type nodes; k,v staged bf16 in LDS, q streamed out.
// Phase 2 (VALU): tab[pos][et] = { kwt = k·Watt·pri/4 | vt = v·Wmsg }, contiguous stores.
// FULL=0 fallback: kb + vt only (R14 semantics).

template<int FULL>
__global__ __launch_bounds__(256) void k_qkv_mfma(
        const float* __restrict__ h, const int* __restrict__ perm, const int* __restrict__ ntype,
        const float* __restrict__ Wk, const float* __restrict__ Wq, const float* __restrict__ Wv,
        const unsigned short* __restrict__ WkB, const unsigned short* __restrict__ WqB,
        const unsigned short* __restrict__ WvB,
        const float* __restrict__ rattT, const float* __restrict__ rmsgT,
        unsigned short* __restrict__ kb, float* __restrict__ qout,
        unsigned short* __restrict__ vt, unsigned short* __restrict__ tab, int n) {
    int tid = threadIdx.x;
    int base = blockIdx.x * MT;
    __shared__ int nodes_s[MT];
    __shared__ int types_s[MT];
    __shared__ unsigned short vs[MT][136];   // bf16 v rows (272B stride, 16B-aligned)
    __shared__ unsigned short ks[MT][136];   // bf16 k rows

    if (tid < MT) {
        int idx = base + tid;
        int nd = (idx < n) ? perm[idx] : -1;
        nodes_s[tid] = nd;
        types_s[tid] = (nd >= 0) ? ntype[nd] : -1;
    }
    __syncthreads();
    bool same = (nodes_s[MT - 1] >= 0) && (types_s[0] == types_s[MT - 1]);
    int l = tid & 63, w = tid >> 6;

    if (same) {
        int t = types_s[0];
        const unsigned short* wbk = WkB + (size_t)t * 16384;
        const unsigned short* wbq = WqB + (size_t)t * 16384;
        const unsigned short* wbv = WvB + (size_t)t * 16384;
        f32x4 acc[3][2][2];
        #pragma unroll
        for (int m = 0; m < 3; m++)
            #pragma unroll
            for (int a = 0; a < 2; a++)
                #pragma unroll
                for (int b = 0; b < 2; b++) {
                    acc[m][a][b][0] = 0.f; acc[m][a][b][1] = 0.f;
                    acc[m][a][b][2] = 0.f; acc[m][a][b][3] = 0.f;
                }
        #pragma unroll 1
        for (int kc = 0; kc < 4; kc++) {
            int koff = kc * 32 + ((l >> 4) << 3);
            int r0 = l & 15;
            const float4* p0 = (const float4*)(h + (size_t)nodes_s[r0] * DIM + koff);
            bf16x8 a0 = pack8(p0[0], p0[1]);
            const float4* p1 = (const float4*)(h + (size_t)nodes_s[16 + r0] * DIM + koff);
            bf16x8 a1 = pack8(p1[0], p1[1]);
            #pragma unroll
            for (int cti = 0; cti < 2; cti++) {
                int boff = ((w * 2 + cti) * 4 + kc) * 512 + l * 8;
                bf16x8 bk = *(const bf16x8*)(wbk + boff);
                acc[0][0][cti] = __builtin_amdgcn_mfma_f32_16x16x32_bf16(a0, bk, acc[0][0][cti], 0, 0, 0);
                acc[0][1][cti] = __builtin_amdgcn_mfma_f32_16x16x32_bf16(a1, bk, acc[0][1][cti], 0, 0, 0);
                bf16x8 bq = *(const bf16x8*)(wbq + boff);
                acc[1][0][cti] = __builtin_amdgcn_mfma_f32_16x16x32_bf16(a0, bq, acc[1][0][cti], 0, 0, 0);
                acc[1][1][cti] = __builtin_amdgcn_mfma_f32_16x16x32_bf16(a1, bq, acc[1][1][cti], 0, 0, 0);
                bf16x8 bv = *(const bf16x8*)(wbv + boff);
                acc[2][0][cti] = __builtin_amdgcn_mfma_f32_16x16x32_bf16(a0, bv, acc[2][0][cti], 0, 0, 0);
                acc[2][1][cti] = __builtin_amdgcn_mfma_f32_16x16x32_bf16(a1, bv, acc[2][1][cti], 0, 0, 0);
            }
        }
        // D lane map: col = lane&15, row = (lane>>4)*4 + r; pos-space streaming q
        #pragma unroll
        for (int mt = 0; mt < 2; mt++)
            #pragma unroll
            for (int cti = 0; cti < 2; cti++) {
                int col = w * 32 + cti * 16 + (l & 15);
                #pragma unroll
                for (int r = 0; r < 4; r++) {
                    int row = mt * 16 + ((l >> 4) << 2) + r;
                    size_t p = (size_t)(base + row) * DIM + col;
                    qout[p] = acc[1][mt][cti][r];
                    vs[row][col] = f2bf(acc[2][mt][cti][r]);
                    unsigned short kv = f2bf(acc[0][mt][cti][r]);
                    ks[row][col] = kv;
                    if constexpr (!FULL) kb[p] = kv;
                }
            }
    } else {
        // scalar fallback (type-boundary / tail blocks)
        int o = tid & 127, half = tid >> 7;
        for (int nn = half; nn < MT; nn += 2) {
            int nd = nodes_s[nn];
            if (nd < 0) { vs[nn][o] = 0; ks[nn][o] = 0; continue; }
            int t = types_s[nn];
            const float* wk = Wk + (size_t)t * 16384;
            const float* wq = Wq + (size_t)t * 16384;
            const float* wv = Wv + (size_t)t * 16384;
            float ak = 0.f, aq = 0.f, av = 0.f;
            for (int d = 0; d < DIM; d++) {
                float xv = h[(size_t)nd * DIM + d];
                ak = fmaf(xv, wk[d * DIM + o], ak);
                aq = fmaf(xv, wq[d * DIM + o], aq);
                av = fmaf(xv, wv[d * DIM + o], av);
            }
            size_t p = (size_t)(base + nn) * DIM + o;
            qout[p] = aq;
            vs[nn][o] = f2bf(av);
            unsigned short kv = f2bf(ak);
            ks[nn][o] = kv;
            if constexpr (!FULL) kb[p] = kv;
        }
    }
    __syncthreads();

    // ---- phase 2 (VALU): streaming table build ----
    {
        int o = tid & 127, half = tid >> 7;
        int hh = o >> 4, oo = o & 15;
        #pragma unroll 1
        for (int et = 0; et < NREL; et++) {
            const float4* wm4 = (const float4*)(rmsgT + ((size_t)(hh * NREL + et) * HDIM + oo) * HDIM);
            float4 m0 = wm4[0], m1 = wm4[1], m2 = wm4[2], m3 = wm4[3];
            float4 a0, a1, a2, a3;
            if constexpr (FULL) {
                const float4* wa4 = (const float4*)(rattT + ((size_t)(hh * NREL + et) * HDIM + oo) * HDIM);
                a0 = wa4[0]; a1 = wa4[1]; a2 = wa4[2]; a3 = wa4[3];
            }
            for (int i = 0; i < 16; i++) {
                int nn = half * 16 + i;
                if (base + nn >= n) continue;
                const uint4* vr = (const uint4*)&vs[nn][hh * HDIM];
                uint4 v0 = vr[0], v1 = vr[1];
                float vv = blo(v0.x)*m0.x + bhi(v0.x)*m0.y + blo(v0.y)*m0.z + bhi(v0.y)*m0.w
                         + blo(v0.z)*m1.x + bhi(v0.z)*m1.y + blo(v0.w)*m1.z + bhi(v0.w)*m1.w
                         + blo(v1.x)*m2.x + bhi(v1.x)*m2.y + blo(v1.y)*m2.z + bhi(v1.y)*m2.w
                         + blo(v1.z)*m3.x + bhi(v1.z)*m3.y + blo(v1.w)*m3.z + bhi(v1.w)*m3.w;
                if constexpr (FULL) {
                    const uint4* kr = (const uint4*)&ks[nn][hh * HDIM];
                    uint4 k0 = kr[0], k1 = kr[1];
                    float kw = blo(k0.x)*a0.x + bhi(k0.x)*a0.y + blo(k0.y)*a0.z + bhi(k0.y)*a0.w
                             + blo(k0.z)*a1.x + bhi(k0.z)*a1.y + blo(k0.w)*a1.z + bhi(k0.w)*a1.w
                             + blo(k1.x)*a2.x + bhi(k1.x)*a2.y + blo(k1.y)*a2.z + bhi(k1.y)*a2.w
                             + blo(k1.z)*a3.x + bhi(k1.z)*a3.y + blo(k1.w)*a3.z + bhi(k1.w)*a3.w;
                    size_t tb = ((size_t)(base + nn) * NREL + et) * 256;
                    tab[tb + o] = f2bf(kw);
                    tab[tb + 128 + o] = f2bf(vv);
                } else {
                    vt[((size_t)(base + nn) * NREL + et) * DIM + o] = f2bf(vv);
                }
            }
        }
    }
}

// ======= fused attention v12 (FULL path): kwt gather, no u-compute =======

__global__ __launch_bounds__(128) void k_fused12(
        const unsigned short* __restrict__ tab, const float* __restrict__ qbuf,
        const int* __restrict__ perm,
        const int* __restrict__ rs2, const int* __restrict__ epk,
        float* __restrict__ agg) {
    int b = blockIdx.x;
    int node = perm[b];
    int tid = threadIdx.x;
    int hh = tid >> 4, oo = tid & 15;
    int wv = tid >> 6;
    int hl = hh & 3;

    __shared__ float q_s[DIM];
    __shared__ float a_sw[2][4][HDIM + 1];
    __shared__ int   es_sw[2][HDIM];

    int e0 = rs2[node * NREL];
    int e1 = rs2[node * NREL + NREL];
    if (e0 == e1) { agg[(size_t)b * DIM + tid] = 0.f; return; }

    q_s[tid] = qbuf[(size_t)b * DIM + tid];
    const float4* q4 = (const float4*)&q_s[hh * HDIM];   // intra-wave LDS, in-order
    float4 q0 = q4[0], q1 = q4[1], q2 = q4[2], q3 = q4[3];

    float m_h = -1e30f, s_h = 0.f, out = 0.f;

    for (int w0e = e0; w0e < e1; w0e += HDIM) {
        int cnt = min(HDIM, e1 - w0e);
        float a = -1e30f;
        int pk = 0;
        if (oo < cnt) {
            pk = epk[w0e + oo];
            int sv = pk & 0x00FFFFFF;
            int et = ((unsigned)pk) >> 24;
            const uint4* kw = (const uint4*)(tab + ((size_t)sv * NREL + et) * 256 + hh * HDIM);
            uint4 ka = kw[0], kc = kw[1];
            a = blo(ka.x)*q0.x + bhi(ka.x)*q0.y + blo(ka.y)*q0.z + bhi(ka.y)*q0.w
              + blo(ka.z)*q1.x + bhi(ka.z)*q1.y + blo(ka.w)*q1.z + bhi(ka.w)*q1.w
              + blo(kc.x)*q2.x + bhi(kc.x)*q2.y + blo(kc.y)*q2.z + bhi(kc.y)*q2.w
              + blo(kc.z)*q3.x + bhi(kc.z)*q3.y + blo(kc.w)*q3.z + bhi(kc.w)*q3.w;
        }
        if (hl == 0) es_sw[wv][oo] = pk;
        float cmax = a;
        cmax = fmaxf(cmax, __shfl_xor(cmax, 1));
        cmax = fmaxf(cmax, __shfl_xor(cmax, 2));
        cmax = fmaxf(cmax, __shfl_xor(cmax, 4));
        cmax = fmaxf(cmax, __shfl_xor(cmax, 8));
        float m_t = (cmax > m_h + 12.f) ? cmax : m_h;   // deferred rescale
        float r = __expf(m_h - m_t);
        s_h *= r; out *= r; m_h = m_t;
        float p = (oo < cnt) ? __expf(a - m_h) : 0.f;
        float ps = p;
        ps += __shfl_xor(ps, 1);
        ps += __shfl_xor(ps, 2);
        ps += __shfl_xor(ps, 4);
        ps += __shfl_xor(ps, 8);
        s_h += ps;
        a_sw[wv][hl][oo] = p;
        for (int c = 0; c < cnt; c++) {
            float pc = a_sw[wv][hl][c];
            int pkc = es_sw[wv][c];
            int sv = pkc & 0x00FFFFFF;
            int et = ((unsigned)pkc) >> 24;
            unsigned short uv = tab[((size_t)sv * NREL + et) * 256 + 128 + tid];
            out = fmaf(pc, __uint_as_float((unsigned)uv << 16), out);
        }
    }

    agg[(size_t)b * DIM + tid] = out / (s_h + 1e-9f);
}

// ======= fused attention v11 (fallback path, R14-identical) =======

__global__ __launch_bounds__(128) void k_fused11(
        const unsigned short* __restrict__ kb, const float* __restrict__ qbuf,
        const unsigned short* __restrict__ vt,
        const int* __restrict__ perm,
        const int* __restrict__ rs2, const int* __restrict__ epk,
        const unsigned short* __restrict__ rattB, const float* __restrict__ rpri,
        float* __restrict__ agg) {
    int b = blockIdx.x;
    int node = perm[b];
    int tid = threadIdx.x;
    int hh = tid >> 4, oo = tid & 15;
    int wv = tid >> 6;
    int hl = hh & 3;

    __shared__ float q_s[DIM];
    __shared__ float u_s[NREL][NHEAD * HDIM + 4];
    __shared__ float a_sw[2][4][HDIM + 1];
    __shared__ int   es_sw[2][HDIM];

    int e0 = rs2[node * NREL];
    int e1 = rs2[node * NREL + NREL];
    if (e0 == e1) { agg[(size_t)b * DIM + tid] = 0.f; return; }

    q_s[tid] = qbuf[(size_t)b * DIM + tid];
    {
        const float4* q4 = (const float4*)&q_s[hh * HDIM];
        float4 q0 = q4[0], q1 = q4[1], q2 = q4[2], q3 = q4[3];
        #pragma unroll
        for (int et = 0; et < NREL; et++) {
            const uint4* wB = (const uint4*)(rattB + ((size_t)(hh * NREL + et) * HDIM + oo) * HDIM);
            uint4 wa = wB[0], wb = wB[1];
            float s = blo(wa.x)*q0.x + bhi(wa.x)*q0.y + blo(wa.y)*q0.z + bhi(wa.y)*q0.w
                    + blo(wa.z)*q1.x + bhi(wa.z)*q1.y + blo(wa.w)*q1.z + bhi(wa.w)*q1.w
                    + blo(wb.x)*q2.x + bhi(wb.x)*q2.y + blo(wb.y)*q2.z + bhi(wb.y)*q2.w
                    + blo(wb.z)*q3.x + bhi(wb.z)*q3.y + blo(wb.w)*q3.z + bhi(wb.w)*q3.w;
            u_s[et][tid] = s * rpri[hh * NREL + et] * 0.25f;
        }
    }

    float m_h = -1e30f, s_h = 0.f, out = 0.f;

    for (int w0e = e0; w0e < e1; w0e += HDIM) {
        int cnt = min(HDIM, e1 - w0e);
        float a = -1e30f;
        int pk = 0;
        if (oo < cnt) {
            pk = epk[w0e + oo];
            int sv = pk & 0x00FFFFFF;
            int et = ((unsigned)pk) >> 24;
            const uint4* kr = (const uint4*)(kb + (size_t)sv * DIM + hh * HDIM);
            uint4 ka = kr[0], kc = kr[1];
            const float4* u4 = (const float4*)&u_s[et][hh * HDIM];
            float4 u0 = u4[0], u1 = u4[1], u2 = u4[2], u3 = u4[3];
            a = blo(ka.x)*u0.x + bhi(ka.x)*u0.y + blo(ka.y)*u0.z + bhi(ka.y)*u0.w
              + blo(ka.z)*u1.x + bhi(ka.z)*u1.y + blo(ka.w)*u1.z + bhi(ka.w)*u1.w
              + blo(kc.x)*u2.x + bhi(kc.x)*u2.y + blo(kc.y)*u2.z + bhi(kc.y)*u2.w
              + blo(kc.z)*u3.x + bhi(kc.z)*u3.y + blo(kc.w)*u3.z + bhi(kc.w)*u3.w;
        }
        if (hl == 0) es_sw[wv][oo] = pk;
        float cmax = a;
        cmax = fmaxf(cmax, __shfl_xor(cmax, 1));
        cmax = fmaxf(cmax, __shfl_xor(cmax, 2));
        cmax = fmaxf(cmax, __shfl_xor(cmax, 4));
        cmax = fmaxf(cmax, __shfl_xor(cmax, 8));
        float m_t = (cmax > m_h + 12.f) ? cmax : m_h;
        float r = __expf(m_h - m_t);
        s_h *= r; out *= r; m_h = m_t;
        float p = (oo < cnt) ? __expf(a - m_h) : 0.f;
        float ps = p;
        ps += __shfl_xor(ps, 1);
        ps += __shfl_xor(ps, 2);
        ps += __shfl_xor(ps, 4);
        ps += __shfl_xor(ps, 8);
        s_h += ps;
        a_sw[wv][hl][oo] = p;
        for (int c = 0; c < cnt; c++) {
            float pc = a_sw[wv][hl][c];
            int pkc = es_sw[wv][c];
            int sv = pkc & 0x00FFFFFF;
            int et = ((unsigned)pkc) >> 24;
            unsigned short uv = vt[((size_t)sv * NREL + et) * DIM + tid];
            out = fmaf(pc, __uint_as_float((unsigned)uv << 16), out);
        }
    }

    agg[(size_t)b * DIM + tid] = out / (s_h + 1e-9f);
}

// ====== output projection + skip + LN + residual (pos-space agg read) ======

__global__ __launch_bounds__(128) void k_out_g(
        const float* __restrict__ agg, float* __restrict__ h,
        const int* __restrict__ perm, const int* __restrict__ ntype,
        const float* __restrict__ Wa, const float* __restrict__ skip,
        const float* __restrict__ ln_g, const float* __restrict__ ln_b, int n) {
    int o = threadIdx.x;
    int base = blockIdx.x * GN;
    __shared__ float xs[GN][DIM];
    __shared__ float hcs[GN][DIM + 1];
    __shared__ int nodes[GN];
    __shared__ int types[GN];
    __shared__ float mu_s[GN], rs_s[GN];
    if (o < GN) {
        int idx = base + o;
        int nd = (idx < n) ? perm[idx] : -1;
        nodes[o] = nd;
        types[o] = (nd >= 0) ? ntype[nd] : -1;
    }
    __syncthreads();
    #pragma unroll
    for (int nn = 0; nn < GN; nn++)
        if (nodes[nn] >= 0) xs[nn][o] = agg[(size_t)(base + nn) * DIM + o];
    __syncthreads();
    bool same = (nodes[GN - 1] >= 0) && (types[0] == types[GN - 1]);
    if (same) {
        int t = types[0];
        const float* w = Wa + (size_t)t * DIM * DIM;
        float acc[GN];
        #pragma unroll
        for (int nn = 0; nn < GN; nn++) acc[nn] = 0.f;
        for (int d = 0; d < DIM; d++) {
            float wv = w[d * DIM + o];
            #pragma unroll
            for (int nn = 0; nn < GN; nn++) acc[nn] = fmaf(xs[nn][d], wv, acc[nn]);
        }
        float alpha = 1.f / (1.f + __expf(-skip[t]));
        #pragma unroll
        for (int nn = 0; nn < GN; nn++) {
            float hp = h[(size_t)nodes[nn] * DIM + o];
            hcs[nn][o] = acc[nn] * alpha + hp * (1.f - alpha);
        }
    } else {
        #pragma unroll 1
        for (int nn = 0; nn < GN; nn++) {
            if (nodes[nn] < 0) continue;
            int t = types[nn];
            const float* w = Wa + (size_t)t * DIM * DIM;
            float a0 = 0.f;
            for (int d = 0; d < DIM; d++) a0 = fmaf(xs[nn][d], w[d * DIM + o], a0);
            float alpha = 1.f / (1.f + __expf(-skip[t]));
            float hp = h[(size_t)nodes[nn] * DIM + o];
            hcs[nn][o] = a0 * alpha + hp * (1.f - alpha);
        }
    }
    __syncthreads();
    {
        int g = o >> 4, j = o & 15;
        if (nodes[g] >= 0) {
            float s = 0.f;
            for (int d = j; d < DIM; d += 16) s += hcs[g][d];
            #pragma unroll
            for (int m = 1; m < 16; m <<= 1) s += __shfl_xor(s, m);
            float mu = s * (1.f / DIM);
            float v = 0.f;
            for (int d = j; d < DIM; d += 16) { float dv = hcs[g][d] - mu; v = fmaf(dv, dv, v); }
            #pragma unroll
            for (int m = 1; m < 16; m <<= 1) v += __shfl_xor(v, m);
            if (j == 0) { mu_s[g] = mu; rs_s[g] = rsqrtf(v * (1.f / DIM) + 1e-5f); }
        }
    }
    __syncthreads();
    float g_o = ln_g[o], b_o = ln_b[o];
    #pragma unroll
    for (int nn = 0; nn < GN; nn++) {
        if (nodes[nn] >= 0) {
            float hp = h[(size_t)nodes[nn] * DIM + o];
            h[(size_t)nodes[nn] * DIM + o] = (hcs[nn][o] - mu_s[nn]) * rs_s[nn] * g_o + b_o + hp;
        }
    }
}

// ================= host =================

extern "C" void kernel_launch(void* const* d_in, const int* in_sizes, int n_in,
                              void* d_out, int out_size, void* d_ws, size_t ws_size,
                              hipStream_t stream) {
    const float* embed = (const float*)d_in[0];
    const float* Wk    = (const float*)d_in[1];
    const float* Wq    = (const float*)d_in[2];
    const float* Wv    = (const float*)d_in[3];
    const float* Wa    = (const float*)d_in[4];
    const float* ratt  = (const float*)d_in[5];
    const float* rmsg  = (const float*)d_in[6];
    const float* rpri  = (const float*)d_in[7];
    const float* skip  = (const float*)d_in[8];
    const float* ln_g  = (const float*)d_in[9];
    const float* ln_b  = (const float*)d_in[10];
    const int*   src   = (const int*)d_in[11];
    const int*   dst   = (const int*)d_in[12];
    const int*   ntype = (const int*)d_in[13];
    const int*   etype = (const int*)d_in[14];

    float* h = (float*)d_out;

    const size_t ND = (size_t)N_NODES * DIM;
    const int nb = (N_NODES + RB - 1) / RB;
    unsigned short* kb = (unsigned short*)d_ws;          // ND bf16 (fallback only)
    float* qbuf = (float*)(kb + ND);                     // ND f32 (pos-space; aliased agg)
    int* rs2  = (int*)(qbuf + ND);               // NK+1
    int* deg2 = rs2 + (NK + 1);                  // NK
    int* cur2 = deg2 + NK;                       // NK
    int* epk  = cur2 + NK;                       // E
    int* bsum = epk + NEDGE;                     // 2048
    int* rank = bsum + 2048;                     // N
    int* hist = rank + N_NODES;                  // nb*NTYPE
    int* boff = hist + nb * NTYPE;               // nb*NTYPE
    int* typeoff = boff + nb * NTYPE;            // NTYPE
    int* perm = typeoff + NTYPE;                 // N
    int* iperm = perm + N_NODES;                 // N
    float* rmsgT = (float*)(iperm + N_NODES);    // LHR*256 f32
    float* rattT = rmsgT + (size_t)LHR * 256;    // LHR*256 f32 (pri-scaled)
    unsigned short* rattB = (unsigned short*)(rattT + (size_t)LHR * 256);  // LHR*256 bf16 (fallback)
    unsigned short* wpk = rattB + (size_t)LHR * 256;                       // L*3*T*16384
    unsigned short* vt  = wpk + (size_t)NLAYER * 3 * NTYPE * 16384;        // N*R*128 (fallback)
    unsigned short* tab = vt;                                              // N*R*256 (full)
    size_t need_full = (size_t)((char*)(tab + (size_t)N_NODES * NREL * 256) - (char*)d_ws);
    const bool FULL = (ws_size >= need_full);
    float* agg = qbuf;

    const int EB = (NEDGE + 255) / 256;
    const int nb2 = (NK + 255) / 256;

    // ---- init: rank-within-type, embedding, type permutation ----
    k_hist<<<nb, RB, 0, stream>>>(ntype, hist, N_NODES);
    k_prefix<<<1, 64, 0, stream>>>(hist, boff, nb);
    k_rank<<<nb, RB, 0, stream>>>(ntype, boff, rank, N_NODES);
    k_embed<<<N_NODES, DIM, 0, stream>>>(embed, ntype, rank, h);
    k_typeoff<<<1, 64, 0, stream>>>(hist, boff, nb, typeoff);
    k_perm<<<nb, 256, 0, stream>>>(ntype, rank, typeoff, perm, iperm, N_NODES);

    // ---- (dst,etype)-sorted CSR build ----
    hipMemsetAsync(deg2, 0, (size_t)NK * sizeof(int), stream);
    hipMemsetAsync(cur2, 0, (size_t)NK * sizeof(int), stream);
    k_deg2<<<EB, 256, 0, stream>>>(dst, etype, deg2);
    k_scan1<<<nb2, 256, 0, stream>>>(deg2, rs2, bsum, NK);
    k_scan2b<<<1, 256, 0, stream>>>(bsum, nb2);
    k_scan3<<<nb2, 256, 0, stream>>>(rs2, bsum, NK);
    k_scatter2<<<EB, 256, 0, stream>>>(src, dst, etype, iperm, rs2, cur2, epk);

    // ---- weight prep (all layers, one launch each) ----
    k_rmsgT<<<LHR, 256, 0, stream>>>(rmsg, rmsgT);
    k_rattT<<<LHR, 256, 0, stream>>>(ratt, rpri, rattT);
    k_rattB<<<LHR, 256, 0, stream>>>(ratt, rattB);
    k_packW_all<<<NLAYER * 3 * NTYPE, 256, 0, stream>>>(Wk, Wq, Wv, wpk);

    const int NGB = N_NODES / GN;            // 6250
    const int NMB = (N_NODES + MT - 1) / MT; // 1563

    for (int l = 0; l < NLAYER; l++) {
        const float* Wk_l = Wk + (size_t)l * NTYPE * DIM * DIM;
        const float* Wq_l = Wq + (size_t)l * NTYPE * DIM * DIM;
        const float* Wv_l = Wv + (size_t)l * NTYPE * DIM * DIM;
        const float* Wa_l = Wa + (size_t)l * NTYPE * DIM * DIM;
        const unsigned short* wkB_l = wpk + ((size_t)l * 3 + 0) * NTYPE * 16384;
        const unsigned short* wqB_l = wpk + ((size_t)l * 3 + 1) * NTYPE * 16384;
        const unsigned short* wvB_l = wpk + ((size_t)l * 3 + 2) * NTYPE * 16384;
        const unsigned short* rattB_l = rattB + (size_t)l * NHEAD * NREL * 256;
        const float* rattT_l = rattT + (size_t)l * NHEAD * NREL * 256;
        const float* rmsgT_l = rmsgT + (size_t)l * NHEAD * NREL * 256;
        const float* rpri_l = rpri + (size_t)l * NHEAD * NREL;
        const float* skip_l = skip + (size_t)l * NTYPE;
        const float* g_l = ln_g + (size_t)l * DIM;
        const float* b_l = ln_b + (size_t)l * DIM;

        if (FULL) {
            k_qkv_mfma<1><<<NMB, 256, 0, stream>>>(h, perm, ntype, Wk_l, Wq_l, Wv_l,
                                                   wkB_l, wqB_l, wvB_l, rattT_l, rmsgT_l,
                                                   kb, qbuf, vt, tab, N_NODES);
            k_fused12<<<N_NODES, 128, 0, stream>>>(tab, qbuf, perm, rs2, epk, agg);
        } else {
            k_qkv_mfma<0><<<NMB, 256, 0, stream>>>(h, perm, ntype, Wk_l, Wq_l, Wv_l,
                                                   wkB_l, wqB_l, wvB_l, rattT_l, rmsgT_l,
                                                   kb, qbuf, vt, tab, N_NODES);
            k_fused11<<<N_NODES, 128, 0, stream>>>(kb, qbuf, vt, perm, rs2, epk,
                                                   rattB_l, rpri_l, agg);
        }
        k_out_g<<<NGB, 128, 0, stream>>>(agg, h, perm, ntype, Wa_l, skip_l, g_l, b_l, N_NODES);
    }
}

// Round 17
// 713.561 us; speedup vs baseline: 1.2178x; 1.0960x over previous
//
#include <hip/hip_runtime.h>
#include <math.h>

#define N_NODES 50000
#define DIM     128
#define NHEAD   8
#define HDIM    16
#define NLAYER  2
#define NTYPE   4
#define NREL    8
#define NEDGE   800000
#define RB      256
#define GN      8      // nodes per block in k_out_g
#define MT      32     // nodes per block in MFMA qkv kernel
#define NK      (N_NODES * NREL)
#define LHR     (NLAYER * NHEAD * NREL)

typedef __attribute__((ext_vector_type(8))) short bf16x8;   // 8 bf16 (4 VGPRs)
typedef __attribute__((ext_vector_type(4))) float f32x4;    // MFMA accumulator

__device__ __forceinline__ float blo(unsigned w) { return __uint_as_float(w << 16); }
__device__ __forceinline__ float bhi(unsigned w) { return __uint_as_float(w & 0xFFFF0000u); }
__device__ __forceinline__ unsigned short f2bf(float f) {
    unsigned b = __float_as_uint(f);
    b += 0x7FFFu + ((b >> 16) & 1u);
    return (unsigned short)(b >> 16);
}
__device__ __forceinline__ bf16x8 pack8(float4 x0, float4 x1) {
    bf16x8 r;
    r[0] = (short)f2bf(x0.x); r[1] = (short)f2bf(x0.y);
    r[2] = (short)f2bf(x0.z); r[3] = (short)f2bf(x0.w);
    r[4] = (short)f2bf(x1.x); r[5] = (short)f2bf(x1.y);
    r[6] = (short)f2bf(x1.z); r[7] = (short)f2bf(x1.w);
    return r;
}
__device__ __forceinline__ bf16x8 zero8() {
    bf16x8 r;
    #pragma unroll
    for (int j = 0; j < 8; j++) r[j] = 0;
    return r;
}

// ================= init: rank within type =================

__global__ void k_hist(const int* __restrict__ ntype, int* __restrict__ hist, int n) {
    __shared__ int cnt[NTYPE];
    if (threadIdx.x < NTYPE) cnt[threadIdx.x] = 0;
    __syncthreads();
    int i = blockIdx.x * RB + threadIdx.x;
    if (i < n) atomicAdd(&cnt[ntype[i]], 1);
    __syncthreads();
    if (threadIdx.x < NTYPE) hist[blockIdx.x * NTYPE + threadIdx.x] = cnt[threadIdx.x];
}

__global__ void k_prefix(const int* __restrict__ hist, int* __restrict__ off, int nb) {
    int t = threadIdx.x;
    if (t >= NTYPE) return;
    int acc = 0;
    for (int b = 0; b < nb; b++) { off[b * NTYPE + t] = acc; acc += hist[b * NTYPE + t]; }
}

__global__ void k_rank(const int* __restrict__ ntype, const int* __restrict__ off,
                       int* __restrict__ rank, int n) {
    __shared__ int ty[RB];
    int i = blockIdx.x * RB + threadIdx.x;
    int t = (i < n) ? ntype[i] : -1;
    ty[threadIdx.x] = t;
    __syncthreads();
    if (i < n) {
        int c = 0;
        for (int j = 0; j < (int)threadIdx.x; j++) c += (ty[j] == t);
        rank[i] = off[blockIdx.x * NTYPE + t] + c;
    }
}

__global__ void k_embed(const float* __restrict__ embed, const int* __restrict__ ntype,
                        const int* __restrict__ rank, float* __restrict__ h) {
    int i = blockIdx.x;
    int t = ntype[i], r = rank[i];
    h[(size_t)i * DIM + threadIdx.x] = embed[((size_t)t * N_NODES + r) * DIM + threadIdx.x];
}

__global__ void k_typeoff(const int* __restrict__ hist, const int* __restrict__ boff,
                          int nb, int* __restrict__ typeoff) {
    if (threadIdx.x == 0 && blockIdx.x == 0) {
        int acc = 0;
        for (int t = 0; t < NTYPE; t++) {
            typeoff[t] = acc;
            acc += boff[(nb - 1) * NTYPE + t] + hist[(nb - 1) * NTYPE + t];
        }
    }
}

__global__ void k_perm(const int* __restrict__ ntype, const int* __restrict__ rank,
                       const int* __restrict__ typeoff, int* __restrict__ perm,
                       int* __restrict__ iperm, int n) {
    int i = blockIdx.x * 256 + threadIdx.x;
    if (i < n) {
        int p = typeoff[ntype[i]] + rank[i];
        perm[p] = i;
        iperm[i] = p;
    }
}

// ================= (dst,etype)-sorted CSR build =================

__global__ void k_deg2(const int* __restrict__ dst, const int* __restrict__ etype,
                       int* __restrict__ deg) {
    int e = blockIdx.x * 256 + threadIdx.x;
    if (e < NEDGE) atomicAdd(&deg[dst[e] * NREL + etype[e]], 1);
}

__global__ void k_scan1(const int* __restrict__ deg, int* __restrict__ rs,
                        int* __restrict__ bsum, int n) {
    __shared__ int sh[256];
    int i = blockIdx.x * 256 + threadIdx.x;
    int v = (i < n) ? deg[i] : 0;
    sh[threadIdx.x] = v;
    __syncthreads();
    for (int off = 1; off < 256; off <<= 1) {
        int x = (threadIdx.x >= off) ? sh[threadIdx.x - off] : 0;
        __syncthreads();
        sh[threadIdx.x] += x;
        __syncthreads();
    }
    if (i < n) rs[i] = sh[threadIdx.x] - v;
    if (threadIdx.x == 255) bsum[blockIdx.x] = sh[255];
}

__global__ void k_scan2b(int* __restrict__ bsum, int nb) {
    __shared__ int sh[256];
    __shared__ int carry;
    if (threadIdx.x == 0) carry = 0;
    __syncthreads();
    for (int base = 0; base < nb; base += 256) {
        int i = base + threadIdx.x;
        int v = (i < nb) ? bsum[i] : 0;
        sh[threadIdx.x] = v;
        __syncthreads();
        for (int off = 1; off < 256; off <<= 1) {
            int x = (threadIdx.x >= off) ? sh[threadIdx.x - off] : 0;
            __syncthreads();
            sh[threadIdx.x] += x;
            __syncthreads();
        }
        if (i < nb) bsum[i] = sh[threadIdx.x] - v + carry;
        __syncthreads();
        if (threadIdx.x == 0) carry += sh[255];
        __syncthreads();
    }
}

__global__ void k_scan3(int* __restrict__ rs, const int* __restrict__ bsum, int n) {
    int i = blockIdx.x * 256 + threadIdx.x;
    if (i < n) rs[i] += bsum[blockIdx.x];
    if (i == 0) rs[n] = NEDGE;
}

__global__ void k_scatter2(const int* __restrict__ src, const int* __restrict__ dst,
                           const int* __restrict__ etype, const int* __restrict__ iperm,
                           const int* __restrict__ rs,
                           int* __restrict__ cur, int* __restrict__ epk) {
    int e = blockIdx.x * 256 + threadIdx.x;
    if (e < NEDGE) {
        int et = etype[e];
        int key = dst[e] * NREL + et;
        int p = atomicAdd(&cur[key], 1);
        epk[rs[key] + p] = iperm[src[e]] | (et << 24);
    }
}

// ================= weight prep =================

__global__ void k_rattB(const float* __restrict__ ratt, unsigned short* __restrict__ rattB) {
    int i = blockIdx.x * 256 + threadIdx.x;
    rattB[i] = f2bf(ratt[i]);
}

__global__ void k_rmsgT(const float* __restrict__ rmsg, float* __restrict__ rmsgT) {
    int b = blockIdx.x;
    int d = threadIdx.x >> 4, o = threadIdx.x & 15;
    rmsgT[b * 256 + o * 16 + d] = rmsg[b * 256 + d * 16 + o];
}

// zero-padded-K B-frag for 16x16x32 from rmsg (no scale)
__global__ void k_rmsgBP(const float* __restrict__ rmsg, unsigned short* __restrict__ out) {
    int b = blockIdx.x;                // (l*H + h)*R + et
    int i = threadIdx.x;               // lane*8 + e
    int ln = i >> 3, e = i & 7;
    int half = ln >> 4;
    unsigned short v = 0;
    if (half < 2) v = f2bf(rmsg[(size_t)b * 256 + (half * 8 + e) * 16 + (ln & 15)]);
    out[(size_t)b * 512 + i] = v;
}

// zero-padded-K B-frag from ratt, scaled by pri*0.25 (folds softmax scale)
__global__ void k_rattBP(const float* __restrict__ ratt, const float* __restrict__ rpri,
                         unsigned short* __restrict__ out) {
    int b = blockIdx.x;
    int i = threadIdx.x;
    int ln = i >> 3, e = i & 7;
    int half = ln >> 4;
    int et = b % NREL;
    int hh = (b / NREL) % NHEAD;
    int l = b / (NREL * NHEAD);
    float scale = rpri[(l * NHEAD + hh) * NREL + et] * 0.25f;
    unsigned short v = 0;
    if (half < 2) v = f2bf(ratt[(size_t)b * 256 + (half * 8 + e) * 16 + (ln & 15)] * scale);
    out[(size_t)b * 512 + i] = v;
}

// pack all L*3*T 128x128 typed mats into MFMA B-fragment bf16 layout
__global__ void k_packW_all(const float* __restrict__ Wk, const float* __restrict__ Wq,
                            const float* __restrict__ Wv, unsigned short* __restrict__ wpk) {
    int bid = blockIdx.x;              // (l*3+m)*NTYPE + t
    int t = bid & 3;
    int m = (bid >> 2) % 3;
    int l = bid / 12;
    const float* W = (m == 0 ? Wk : (m == 1 ? Wq : Wv)) + ((size_t)l * NTYPE + t) * 16384;
    unsigned short* ob = wpk + (size_t)bid * 16384;
    for (int idx = threadIdx.x; idx < 16384; idx += 256) {
        int ct = idx >> 11, kc = (idx >> 9) & 3, ln = (idx >> 3) & 63, j = idx & 7;
        int k = kc * 32 + ((ln >> 4) << 3) + j;
        int c = ct * 16 + (ln & 15);
        ob[idx] = f2bf(W[k * 128 + c]);
    }
}

// ======== MFMA typed k/q/v projection + MFMA tab build (LDS-staged streaming) ========
// Phase 1 (MFMA): k,q,v for 32 same-type nodes; k,v staged bf16 in LDS, q streamed out.
// Phase 2 FULL (MFMA): per et, zero-padded-K MFMAs -> D frags into LDS tile -> stream
//   contiguous 512B rows to tab[pos][et][{kwt|vt}].
// FULL=0 fallback: kb + vt via VALU (R14 semantics).

template<int FULL>
__global__ __launch_bounds__(256) void k_qkv_mfma(
        const float* __restrict__ h, const int* __restrict__ perm, const int* __restrict__ ntype,
        const float* __restrict__ Wk, const float* __restrict__ Wq, const float* __restrict__ Wv,
        const unsigned short* __restrict__ WkB, const unsigned short* __restrict__ WqB,
        const unsigned short* __restrict__ WvB,
        const unsigned short* __restrict__ rattBP, const unsigned short* __restrict__ rmsgBP,
        const float* __restrict__ rmsgT,
        unsigned short* __restrict__ kb, float* __restrict__ qout,
        unsigned short* __restrict__ vt, unsigned short* __restrict__ tab, int n) {
    int tid = threadIdx.x;
    int base = blockIdx.x * MT;
    __shared__ int nodes_s[MT];
    __shared__ int types_s[MT];
    __shared__ unsigned short vs[MT][136];   // bf16 v rows (272B stride, 16B-aligned)
    __shared__ unsigned short ks[MT][136];   // bf16 k rows

    if (tid < MT) {
        int idx = base + tid;
        int nd = (idx < n) ? perm[idx] : -1;
        nodes_s[tid] = nd;
        types_s[tid] = (nd >= 0) ? ntype[nd] : -1;
    }
    __syncthreads();
    bool same = (nodes_s[MT - 1] >= 0) && (types_s[0] == types_s[MT - 1]);
    int l = tid & 63, w = tid >> 6;

    if (same) {
        int t = types_s[0];
        const unsigned short* wbk = WkB + (size_t)t * 16384;
        const unsigned short* wbq = WqB + (size_t)t * 16384;
        const unsigned short* wbv = WvB + (size_t)t * 16384;
        f32x4 acc[3][2][2];
        #pragma unroll
        for (int m = 0; m < 3; m++)
            #pragma unroll
            for (int a = 0; a < 2; a++)
                #pragma unroll
                for (int b = 0; b < 2; b++) {
                    acc[m][a][b][0] = 0.f; acc[m][a][b][1] = 0.f;
                    acc[m][a][b][2] = 0.f; acc[m][a][b][3] = 0.f;
                }
        #pragma unroll 1
        for (int kc = 0; kc < 4; kc++) {
            int koff = kc * 32 + ((l >> 4) << 3);
            int r0 = l & 15;
            const float4* p0 = (const float4*)(h + (size_t)nodes_s[r0] * DIM + koff);
            bf16x8 a0 = pack8(p0[0], p0[1]);
            const float4* p1 = (const float4*)(h + (size_t)nodes_s[16 + r0] * DIM + koff);
            bf16x8 a1 = pack8(p1[0], p1[1]);
            #pragma unroll
            for (int cti = 0; cti < 2; cti++) {
                int boff = ((w * 2 + cti) * 4 + kc) * 512 + l * 8;
                bf16x8 bk = *(const bf16x8*)(wbk + boff);
                acc[0][0][cti] = __builtin_amdgcn_mfma_f32_16x16x32_bf16(a0, bk, acc[0][0][cti], 0, 0, 0);
                acc[0][1][cti] = __builtin_amdgcn_mfma_f32_16x16x32_bf16(a1, bk, acc[0][1][cti], 0, 0, 0);
                bf16x8 bq = *(const bf16x8*)(wbq + boff);
                acc[1][0][cti] = __builtin_amdgcn_mfma_f32_16x16x32_bf16(a0, bq, acc[1][0][cti], 0, 0, 0);
                acc[1][1][cti] = __builtin_amdgcn_mfma_f32_16x16x32_bf16(a1, bq, acc[1][1][cti], 0, 0, 0);
                bf16x8 bv = *(const bf16x8*)(wbv + boff);
                acc[2][0][cti] = __builtin_amdgcn_mfma_f32_16x16x32_bf16(a0, bv, acc[2][0][cti], 0, 0, 0);
                acc[2][1][cti] = __builtin_amdgcn_mfma_f32_16x16x32_bf16(a1, bv, acc[2][1][cti], 0, 0, 0);
            }
        }
        // D lane map: col = lane&15, row = (lane>>4)*4 + r; pos-space streaming q
        #pragma unroll
        for (int mt = 0; mt < 2; mt++)
            #pragma unroll
            for (int cti = 0; cti < 2; cti++) {
                int col = w * 32 + cti * 16 + (l & 15);
                #pragma unroll
                for (int r = 0; r < 4; r++) {
                    int row = mt * 16 + ((l >> 4) << 2) + r;
                    size_t p = (size_t)(base + row) * DIM + col;
                    qout[p] = acc[1][mt][cti][r];
                    vs[row][col] = f2bf(acc[2][mt][cti][r]);
                    unsigned short kv = f2bf(acc[0][mt][cti][r]);
                    ks[row][col] = kv;
                    if constexpr (!FULL) kb[p] = kv;
                }
            }
    } else {
        // scalar fallback (type-boundary / tail blocks)
        int o = tid & 127, half = tid >> 7;
        for (int nn = half; nn < MT; nn += 2) {
            int nd = nodes_s[nn];
            if (nd < 0) { vs[nn][o] = 0; ks[nn][o] = 0; continue; }
            int t = types_s[nn];
            const float* wk = Wk + (size_t)t * 16384;
            const float* wq = Wq + (size_t)t * 16384;
            const float* wv = Wv + (size_t)t * 16384;
            float ak = 0.f, aq = 0.f, av = 0.f;
            for (int d = 0; d < DIM; d++) {
                float xv = h[(size_t)nd * DIM + d];
                ak = fmaf(xv, wk[d * DIM + o], ak);
                aq = fmaf(xv, wq[d * DIM + o], aq);
                av = fmaf(xv, wv[d * DIM + o], av);
            }
            size_t p = (size_t)(base + nn) * DIM + o;
            qout[p] = aq;
            vs[nn][o] = f2bf(av);
            unsigned short kv = f2bf(ak);
            ks[nn][o] = kv;
            if constexpr (!FULL) kb[p] = kv;
        }
    }
    __syncthreads();

    if constexpr (FULL) {
        // ---- phase 2 (MFMA, LDS-staged): per et, D frags -> tab_s -> streaming stores ----
        __shared__ unsigned short tab_s[MT][264];   // 528B stride (16B-aligned)
        int half = l >> 4;
        // hoisted A-fragments: k and v rows per (hh-pair, node-tile), loaded ONCE
        bf16x8 afrk[2][2], afrv[2][2];
        #pragma unroll
        for (int hh2 = 0; hh2 < 2; hh2++) {
            int hh = w * 2 + hh2;
            #pragma unroll
            for (int nt = 0; nt < 2; nt++) {
                if (half < 2) {
                    afrk[hh2][nt] = *(const bf16x8*)&ks[nt * 16 + (l & 15)][hh * HDIM + half * 8];
                    afrv[hh2][nt] = *(const bf16x8*)&vs[nt * 16 + (l & 15)][hh * HDIM + half * 8];
                } else {
                    afrk[hh2][nt] = zero8();
                    afrv[hh2][nt] = zero8();
                }
            }
        }
        #pragma unroll 1
        for (int et = 0; et < NREL; et++) {
            #pragma unroll
            for (int hh2 = 0; hh2 < 2; hh2++) {
                int hh = w * 2 + hh2;
                bf16x8 bfa = *(const bf16x8*)(rattBP + ((size_t)(hh * NREL + et) * 64 + l) * 8);
                bf16x8 bfm = *(const bf16x8*)(rmsgBP + ((size_t)(hh * NREL + et) * 64 + l) * 8);
                #pragma unroll
                for (int nt = 0; nt < 2; nt++) {
                    f32x4 dk = {0.f, 0.f, 0.f, 0.f};
                    dk = __builtin_amdgcn_mfma_f32_16x16x32_bf16(afrk[hh2][nt], bfa, dk, 0, 0, 0);
                    f32x4 dv = {0.f, 0.f, 0.f, 0.f};
                    dv = __builtin_amdgcn_mfma_f32_16x16x32_bf16(afrv[hh2][nt], bfm, dv, 0, 0, 0);
                    #pragma unroll
                    for (int r = 0; r < 4; r++) {
                        int row = nt * 16 + half * 4 + r;
                        tab_s[row][hh * HDIM + (l & 15)] = f2bf(dk[r]);
                        tab_s[row][128 + hh * HDIM + (l & 15)] = f2bf(dv[r]);
                    }
                }
            }
            __syncthreads();
            // stream out: 1024 uint4 (32 rows x 512B), contiguous per (node,et) row
            #pragma unroll
            for (int it = 0; it < 4; it++) {
                int idx = it * 256 + tid;
                int row = idx >> 5;
                int c8 = idx & 31;
                if (base + row < n)
                    *(uint4*)&tab[((size_t)(base + row) * NREL + et) * 256 + c8 * 8] =
                        *(const uint4*)&tab_s[row][c8 * 8];
            }
            __syncthreads();
        }
    } else {
        // ---- phase 2 (VALU, R14): vt[pos][et][o], contiguous streaming stores ----
        int o = tid & 127, half = tid >> 7;
        int hh = o >> 4, oo = o & 15;
        #pragma unroll 1
        for (int et = 0; et < NREL; et++) {
            const float4* wm4 = (const float4*)(rmsgT + ((size_t)(hh * NREL + et) * HDIM + oo) * HDIM);
            float4 m0 = wm4[0], m1 = wm4[1], m2 = wm4[2], m3 = wm4[3];
            for (int i = 0; i < 16; i++) {
                int nn = half * 16 + i;
                if (base + nn >= n) continue;
                const uint4* vr = (const uint4*)&vs[nn][hh * HDIM];
                uint4 v0 = vr[0], v1 = vr[1];
                float vv = blo(v0.x)*m0.x + bhi(v0.x)*m0.y + blo(v0.y)*m0.z + bhi(v0.y)*m0.w
                         + blo(v0.z)*m1.x + bhi(v0.z)*m1.y + blo(v0.w)*m1.z + bhi(v0.w)*m1.w
                         + blo(v1.x)*m2.x + bhi(v1.x)*m2.y + blo(v1.y)*m2.z + bhi(v1.y)*m2.w
                         + blo(v1.z)*m3.x + bhi(v1.z)*m3.y + blo(v1.w)*m3.z + bhi(v1.w)*m3.w;
                vt[((size_t)(base + nn) * NREL + et) * DIM + o] = f2bf(vv);
            }
        }
    }
}

// ======= fused attention v12 (FULL path): kwt gather, no u-compute =======

__global__ __launch_bounds__(128) void k_fused12(
        const unsigned short* __restrict__ tab, const float* __restrict__ qbuf,
        const int* __restrict__ perm,
        const int* __restrict__ rs2, const int* __restrict__ epk,
        float* __restrict__ agg) {
    int b = blockIdx.x;
    int node = perm[b];
    int tid = threadIdx.x;
    int hh = tid >> 4, oo = tid & 15;
    int wv = tid >> 6;
    int hl = hh & 3;

    __shared__ float q_s[DIM];
    __shared__ float a_sw[2][4][HDIM + 1];
    __shared__ int   es_sw[2][HDIM];

    int e0 = rs2[node * NREL];
    int e1 = rs2[node * NREL + NREL];
    if (e0 == e1) { agg[(size_t)b * DIM + tid] = 0.f; return; }

    q_s[tid] = qbuf[(size_t)b * DIM + tid];
    const float4* q4 = (const float4*)&q_s[hh * HDIM];   // intra-wave LDS, in-order
    float4 q0 = q4[0], q1 = q4[1], q2 = q4[2], q3 = q4[3];

    float m_h = -1e30f, s_h = 0.f, out = 0.f;

    for (int w0e = e0; w0e < e1; w0e += HDIM) {
        int cnt = min(HDIM, e1 - w0e);
        float a = -1e30f;
        int pk = 0;
        if (oo < cnt) {
            pk = epk[w0e + oo];
            int sv = pk & 0x00FFFFFF;
            int et = ((unsigned)pk) >> 24;
            const uint4* kw = (const uint4*)(tab + ((size_t)sv * NREL + et) * 256 + hh * HDIM);
            uint4 ka = kw[0], kc = kw[1];
            a = blo(ka.x)*q0.x + bhi(ka.x)*q0.y + blo(ka.y)*q0.z + bhi(ka.y)*q0.w
              + blo(ka.z)*q1.x + bhi(ka.z)*q1.y + blo(ka.w)*q1.z + bhi(ka.w)*q1.w
              + blo(kc.x)*q2.x + bhi(kc.x)*q2.y + blo(kc.y)*q2.z + bhi(kc.y)*q2.w
              + blo(kc.z)*q3.x + bhi(kc.z)*q3.y + blo(kc.w)*q3.z + bhi(kc.w)*q3.w;
        }
        if (hl == 0) es_sw[wv][oo] = pk;
        float cmax = a;
        cmax = fmaxf(cmax, __shfl_xor(cmax, 1));
        cmax = fmaxf(cmax, __shfl_xor(cmax, 2));
        cmax = fmaxf(cmax, __shfl_xor(cmax, 4));
        cmax = fmaxf(cmax, __shfl_xor(cmax, 8));
        float m_t = (cmax > m_h + 12.f) ? cmax : m_h;   // deferred rescale
        float r = __expf(m_h - m_t);
        s_h *= r; out *= r; m_h = m_t;
        float p = (oo < cnt) ? __expf(a - m_h) : 0.f;
        float ps = p;
        ps += __shfl_xor(ps, 1);
        ps += __shfl_xor(ps, 2);
        ps += __shfl_xor(ps, 4);
        ps += __shfl_xor(ps, 8);
        s_h += ps;
        a_sw[wv][hl][oo] = p;
        for (int c = 0; c < cnt; c++) {
            float pc = a_sw[wv][hl][c];
            int pkc = es_sw[wv][c];
            int sv = pkc & 0x00FFFFFF;
            int et = ((unsigned)pkc) >> 24;
            unsigned short uv = tab[((size_t)sv * NREL + et) * 256 + 128 + tid];
            out = fmaf(pc, __uint_as_float((unsigned)uv << 16), out);
        }
    }

    agg[(size_t)b * DIM + tid] = out / (s_h + 1e-9f);
}

// ======= fused attention v11 (fallback path, R14-identical) =======

__global__ __launch_bounds__(128) void k_fused11(
        const unsigned short* __restrict__ kb, const float* __restrict__ qbuf,
        const unsigned short* __restrict__ vt,
        const int* __restrict__ perm,
        const int* __restrict__ rs2, const int* __restrict__ epk,
        const unsigned short* __restrict__ rattB, const float* __restrict__ rpri,
        float* __restrict__ agg) {
    int b = blockIdx.x;
    int node = perm[b];
    int tid = threadIdx.x;
    int hh = tid >> 4, oo = tid & 15;
    int wv = tid >> 6;
    int hl = hh & 3;

    __shared__ float q_s[DIM];
    __shared__ float u_s[NREL][NHEAD * HDIM + 4];
    __shared__ float a_sw[2][4][HDIM + 1];
    __shared__ int   es_sw[2][HDIM];

    int e0 = rs2[node * NREL];
    int e1 = rs2[node * NREL + NREL];
    if (e0 == e1) { agg[(size_t)b * DIM + tid] = 0.f; return; }

    q_s[tid] = qbuf[(size_t)b * DIM + tid];
    {
        const float4* q4 = (const float4*)&q_s[hh * HDIM];
        float4 q0 = q4[0], q1 = q4[1], q2 = q4[2], q3 = q4[3];
        #pragma unroll
        for (int et = 0; et < NREL; et++) {
            const uint4* wB = (const uint4*)(rattB + ((size_t)(hh * NREL + et) * HDIM + oo) * HDIM);
            uint4 wa = wB[0], wb = wB[1];
            float s = blo(wa.x)*q0.x + bhi(wa.x)*q0.y + blo(wa.y)*q0.z + bhi(wa.y)*q0.w
                    + blo(wa.z)*q1.x + bhi(wa.z)*q1.y + blo(wa.w)*q1.z + bhi(wa.w)*q1.w
                    + blo(wb.x)*q2.x + bhi(wb.x)*q2.y + blo(wb.y)*q2.z + bhi(wb.y)*q2.w
                    + blo(wb.z)*q3.x + bhi(wb.z)*q3.y + blo(wb.w)*q3.z + bhi(wb.w)*q3.w;
            u_s[et][tid] = s * rpri[hh * NREL + et] * 0.25f;
        }
    }

    float m_h = -1e30f, s_h = 0.f, out = 0.f;

    for (int w0e = e0; w0e < e1; w0e += HDIM) {
        int cnt = min(HDIM, e1 - w0e);
        float a = -1e30f;
        int pk = 0;
        if (oo < cnt) {
            pk = epk[w0e + oo];
            int sv = pk & 0x00FFFFFF;
            int et = ((unsigned)pk) >> 24;
            const uint4* kr = (const uint4*)(kb + (size_t)sv * DIM + hh * HDIM);
            uint4 ka = kr[0], kc = kr[1];
            const float4* u4 = (const float4*)&u_s[et][hh * HDIM];
            float4 u0 = u4[0], u1 = u4[1], u2 = u4[2], u3 = u4[3];
            a = blo(ka.x)*u0.x + bhi(ka.x)*u0.y + blo(ka.y)*u0.z + bhi(ka.y)*u0.w
              + blo(ka.z)*u1.x + bhi(ka.z)*u1.y + blo(ka.w)*u1.z + bhi(ka.w)*u1.w
              + blo(kc.x)*u2.x + bhi(kc.x)*u2.y + blo(kc.y)*u2.z + bhi(kc.y)*u2.w
              + blo(kc.z)*u3.x + bhi(kc.z)*u3.y + blo(kc.w)*u3.z + bhi(kc.w)*u3.w;
        }
        if (hl == 0) es_sw[wv][oo] = pk;
        float cmax = a;
        cmax = fmaxf(cmax, __shfl_xor(cmax, 1));
        cmax = fmaxf(cmax, __shfl_xor(cmax, 2));
        cmax = fmaxf(cmax, __shfl_xor(cmax, 4));
        cmax = fmaxf(cmax, __shfl_xor(cmax, 8));
        float m_t = (cmax > m_h + 12.f) ? cmax : m_h;
        float r = __expf(m_h - m_t);
        s_h *= r; out *= r; m_h = m_t;
        float p = (oo < cnt) ? __expf(a - m_h) : 0.f;
        float ps = p;
        ps += __shfl_xor(ps, 1);
        ps += __shfl_xor(ps, 2);
        ps += __shfl_xor(ps, 4);
        ps += __shfl_xor(ps, 8);
        s_h += ps;
        a_sw[wv][hl][oo] = p;
        for (int c = 0; c < cnt; c++) {
            float pc = a_sw[wv][hl][c];
            int pkc = es_sw[wv][c];
            int sv = pkc & 0x00FFFFFF;
            int et = ((unsigned)pkc) >> 24;
            unsigned short uv = vt[((size_t)sv * NREL + et) * DIM + tid];
            out = fmaf(pc, __uint_as_float((unsigned)uv << 16), out);
        }
    }

    agg[(size_t)b * DIM + tid] = out / (s_h + 1e-9f);
}

// ====== output projection + skip + LN + residual (pos-space agg read) ======

__global__ __launch_bounds__(128) void k_out_g(
        const float* __restrict__ agg, float* __restrict__ h,
        const int* __restrict__ perm, const int* __restrict__ ntype,
        const float* __restrict__ Wa, const float* __restrict__ skip,
        const float* __restrict__ ln_g, const float* __restrict__ ln_b, int n) {
    int o = threadIdx.x;
    int base = blockIdx.x * GN;
    __shared__ float xs[GN][DIM];
    __shared__ float hcs[GN][DIM + 1];
    __shared__ int nodes[GN];
    __shared__ int types[GN];
    __shared__ float mu_s[GN], rs_s[GN];
    if (o < GN) {
        int idx = base + o;
        int nd = (idx < n) ? perm[idx] : -1;
        nodes[o] = nd;
        types[o] = (nd >= 0) ? ntype[nd] : -1;
    }
    __syncthreads();
    #pragma unroll
    for (int nn = 0; nn < GN; nn++)
        if (nodes[nn] >= 0) xs[nn][o] = agg[(size_t)(base + nn) * DIM + o];
    __syncthreads();
    bool same = (nodes[GN - 1] >= 0) && (types[0] == types[GN - 1]);
    if (same) {
        int t = types[0];
        const float* w = Wa + (size_t)t * DIM * DIM;
        float acc[GN];
        #pragma unroll
        for (int nn = 0; nn < GN; nn++) acc[nn] = 0.f;
        for (int d = 0; d < DIM; d++) {
            float wv = w[d * DIM + o];
            #pragma unroll
            for (int nn = 0; nn < GN; nn++) acc[nn] = fmaf(xs[nn][d], wv, acc[nn]);
        }
        float alpha = 1.f / (1.f + __expf(-skip[t]));
        #pragma unroll
        for (int nn = 0; nn < GN; nn++) {
            float hp = h[(size_t)nodes[nn] * DIM + o];
            hcs[nn][o] = acc[nn] * alpha + hp * (1.f - alpha);
        }
    } else {
        #pragma unroll 1
        for (int nn = 0; nn < GN; nn++) {
            if (nodes[nn] < 0) continue;
            int t = types[nn];
            const float* w = Wa + (size_t)t * DIM * DIM;
            float a0 = 0.f;
            for (int d = 0; d < DIM; d++) a0 = fmaf(xs[nn][d], w[d * DIM + o], a0);
            float alpha = 1.f / (1.f + __expf(-skip[t]));
            float hp = h[(size_t)nodes[nn] * DIM + o];
            hcs[nn][o] = a0 * alpha + hp * (1.f - alpha);
        }
    }
    __syncthreads();
    {
        int g = o >> 4, j = o & 15;
        if (nodes[g] >= 0) {
            float s = 0.f;
            for (int d = j; d < DIM; d += 16) s += hcs[g][d];
            #pragma unroll
            for (int m = 1; m < 16; m <<= 1) s += __shfl_xor(s, m);
            float mu = s * (1.f / DIM);
            float v = 0.f;
            for (int d = j; d < DIM; d += 16) { float dv = hcs[g][d] - mu; v = fmaf(dv, dv, v); }
            #pragma unroll
            for (int m = 1; m < 16; m <<= 1) v += __shfl_xor(v, m);
            if (j == 0) { mu_s[g] = mu; rs_s[g] = rsqrtf(v * (1.f / DIM) + 1e-5f); }
        }
    }
    __syncthreads();
    float g_o = ln_g[o], b_o = ln_b[o];
    #pragma unroll
    for (int nn = 0; nn < GN; nn++) {
        if (nodes[nn] >= 0) {
            float hp = h[(size_t)nodes[nn] * DIM + o];
            h[(size_t)nodes[nn] * DIM + o] = (hcs[nn][o] - mu_s[nn]) * rs_s[nn] * g_o + b_o + hp;
        }
    }
}

// ================= host =================

extern "C" void kernel_launch(void* const* d_in, const int* in_sizes, int n_in,
                              void* d_out, int out_size, void* d_ws, size_t ws_size,
                              hipStream_t stream) {
    const float* embed = (const float*)d_in[0];
    const float* Wk    = (const float*)d_in[1];
    const float* Wq    = (const float*)d_in[2];
    const float* Wv    = (const float*)d_in[3];
    const float* Wa    = (const float*)d_in[4];
    const float* ratt  = (const float*)d_in[5];
    const float* rmsg  = (const float*)d_in[6];
    const float* rpri  = (const float*)d_in[7];
    const float* skip  = (const float*)d_in[8];
    const float* ln_g  = (const float*)d_in[9];
    const float* ln_b  = (const float*)d_in[10];
    const int*   src   = (const int*)d_in[11];
    const int*   dst   = (const int*)d_in[12];
    const int*   ntype = (const int*)d_in[13];
    const int*   etype = (const int*)d_in[14];

    float* h = (float*)d_out;

    const size_t ND = (size_t)N_NODES * DIM;
    const int nb = (N_NODES + RB - 1) / RB;
    unsigned short* kb = (unsigned short*)d_ws;          // ND bf16 (fallback only)
    float* qbuf = (float*)(kb + ND);                     // ND f32 (pos-space; aliased agg)
    int* rs2  = (int*)(qbuf + ND);               // NK+1
    int* deg2 = rs2 + (NK + 1);                  // NK
    int* cur2 = deg2 + NK;                       // NK
    int* epk  = cur2 + NK;                       // E
    int* bsum = epk + NEDGE;                     // 2048
    int* rank = bsum + 2048;                     // N
    int* hist = rank + N_NODES;                  // nb*NTYPE
    int* boff = hist + nb * NTYPE;               // nb*NTYPE
    int* typeoff = boff + nb * NTYPE;            // NTYPE
    int* perm = typeoff + NTYPE;                 // N
    int* iperm = perm + N_NODES;                 // N
    float* rmsgT = (float*)(iperm + N_NODES);    // LHR*256 f32
    unsigned short* rattB  = (unsigned short*)(rmsgT + (size_t)LHR * 256);  // LHR*256 bf16
    unsigned short* rattBP = rattB + (size_t)LHR * 256;                     // LHR*512
    unsigned short* rmsgBP = rattBP + (size_t)LHR * 512;                    // LHR*512
    unsigned short* wpk = rmsgBP + (size_t)LHR * 512;                       // L*3*T*16384
    unsigned short* vt  = wpk + (size_t)NLAYER * 3 * NTYPE * 16384;         // N*R*128 (fallback)
    unsigned short* tab = vt;                                               // N*R*256 (full)
    size_t need_full = (size_t)((char*)(tab + (size_t)N_NODES * NREL * 256) - (char*)d_ws);
    const bool FULL = (ws_size >= need_full);
    float* agg = qbuf;

    const int EB = (NEDGE + 255) / 256;
    const int nb2 = (NK + 255) / 256;

    // ---- init: rank-within-type, embedding, type permutation ----
    k_hist<<<nb, RB, 0, stream>>>(ntype, hist, N_NODES);
    k_prefix<<<1, 64, 0, stream>>>(hist, boff, nb);
    k_rank<<<nb, RB, 0, stream>>>(ntype, boff, rank, N_NODES);
    k_embed<<<N_NODES, DIM, 0, stream>>>(embed, ntype, rank, h);
    k_typeoff<<<1, 64, 0, stream>>>(hist, boff, nb, typeoff);
    k_perm<<<nb, 256, 0, stream>>>(ntype, rank, typeoff, perm, iperm, N_NODES);

    // ---- (dst,etype)-sorted CSR build ----
    hipMemsetAsync(deg2, 0, (size_t)NK * sizeof(int), stream);
    hipMemsetAsync(cur2, 0, (size_t)NK * sizeof(int), stream);
    k_deg2<<<EB, 256, 0, stream>>>(dst, etype, deg2);
    k_scan1<<<nb2, 256, 0, stream>>>(deg2, rs2, bsum, NK);
    k_scan2b<<<1, 256, 0, stream>>>(bsum, nb2);
    k_scan3<<<nb2, 256, 0, stream>>>(rs2, bsum, NK);
    k_scatter2<<<EB, 256, 0, stream>>>(src, dst, etype, iperm, rs2, cur2, epk);

    // ---- weight prep (all layers, one launch each) ----
    k_rmsgT<<<LHR, 256, 0, stream>>>(rmsg, rmsgT);
    k_rattB<<<LHR, 256, 0, stream>>>(ratt, rattB);
    k_rattBP<<<LHR, 512, 0, stream>>>(ratt, rpri, rattBP);
    k_rmsgBP<<<LHR, 512, 0, stream>>>(rmsg, rmsgBP);
    k_packW_all<<<NLAYER * 3 * NTYPE, 256, 0, stream>>>(Wk, Wq, Wv, wpk);

    const int NGB = N_NODES / GN;            // 6250
    const int NMB = (N_NODES + MT - 1) / MT; // 1563

    for (int l = 0; l < NLAYER; l++) {
        const float* Wk_l = Wk + (size_t)l * NTYPE * DIM * DIM;
        const float* Wq_l = Wq + (size_t)l * NTYPE * DIM * DIM;
        const float* Wv_l = Wv + (size_t)l * NTYPE * DIM * DIM;
        const float* Wa_l = Wa + (size_t)l * NTYPE * DIM * DIM;
        const unsigned short* wkB_l = wpk + ((size_t)l * 3 + 0) * NTYPE * 16384;
        const unsigned short* wqB_l = wpk + ((size_t)l * 3 + 1) * NTYPE * 16384;
        const unsigned short* wvB_l = wpk + ((size_t)l * 3 + 2) * NTYPE * 16384;
        const unsigned short* rattB_l  = rattB + (size_t)l * NHEAD * NREL * 256;
        const unsigned short* rattBP_l = rattBP + (size_t)l * NHEAD * NREL * 512;
        const unsigned short* rmsgBP_l = rmsgBP + (size_t)l * NHEAD * NREL * 512;
        const float* rmsgT_l = rmsgT + (size_t)l * NHEAD * NREL * 256;
        const float* rpri_l = rpri + (size_t)l * NHEAD * NREL;
        const float* skip_l = skip + (size_t)l * NTYPE;
        const float* g_l = ln_g + (size_t)l * DIM;
        const float* b_l = ln_b + (size_t)l * DIM;

        if (FULL) {
            k_qkv_mfma<1><<<NMB, 256, 0, stream>>>(h, perm, ntype, Wk_l, Wq_l, Wv_l,
                                                   wkB_l, wqB_l, wvB_l,
                                                   rattBP_l, rmsgBP_l, rmsgT_l,
                                                   kb, qbuf, vt, tab, N_NODES);
            k_fused12<<<N_NODES, 128, 0, stream>>>(tab, qbuf, perm, rs2, epk, agg);
        } else {
            k_qkv_mfma<0><<<NMB, 256, 0, stream>>>(h, perm, ntype, Wk_l, Wq_l, Wv_l,
                                                   wkB_l, wqB_l, wvB_l,
                                                   rattBP_l, rmsgBP_l, rmsgT_l,
                                                   kb, qbuf, vt, tab, N_NODES);
            k_fused11<<<N_NODES, 128, 0, stream>>>(kb, qbuf, vt, perm, rs2, epk,
                                                   rattB_l, rpri_l, agg);
        }
        k_out_g<<<NGB, 128, 0, stream>>>(agg, h, perm, ntype, Wa_l, skip_l, g_l, b_l, N_NODES);
    }
}